// Round 2
// baseline (6167.567 us; speedup 1.0000x reference)
//
#include <hip/hip_runtime.h>
#include <math.h>

#define TOK 4096
#define DM 2048
#define DQ 682
#define DCKV 1088
#define DKV 1024
#define DUKV 3072
#define NH 16
#define T_SEQ 2048

// ---------------------------------------------------------------------------
// Generic fp32 GEMM: C[M,N] = A[M,K] (row-major) * B[N,K]^T (row-major) + bias
// 128x64 tile, BK=16, 256 threads, 8x4 microtile.
// ---------------------------------------------------------------------------
__global__ __launch_bounds__(256) void gemm_bt(
    const float* __restrict__ A, const float* __restrict__ B,
    const float* __restrict__ bias, float* __restrict__ C,
    int M, int N, int K)
{
  const int BM = 128, BN = 64, BK = 16;
  __shared__ float As[128][17];
  __shared__ float Bs[64][17];
  int bm = blockIdx.y * BM, bn = blockIdx.x * BN;
  int tid = threadIdx.x;
  int tx = tid & 15, ty = tid >> 4;
  float acc[8][4];
#pragma unroll
  for (int i = 0; i < 8; i++)
#pragma unroll
    for (int j = 0; j < 4; j++) acc[i][j] = 0.f;

  for (int k0 = 0; k0 < K; k0 += BK) {
    for (int idx = tid; idx < BM * BK; idx += 256) {
      int r = idx >> 4, c = idx & 15;
      int gr = bm + r, gc = k0 + c;
      As[r][c] = (gr < M && gc < K) ? A[(size_t)gr * K + gc] : 0.f;
    }
    for (int idx = tid; idx < BN * BK; idx += 256) {
      int r = idx >> 4, c = idx & 15;
      int gr = bn + r, gc = k0 + c;
      Bs[r][c] = (gr < N && gc < K) ? B[(size_t)gr * K + gc] : 0.f;
    }
    __syncthreads();
#pragma unroll
    for (int kk = 0; kk < BK; ++kk) {
      float a[8], b[4];
#pragma unroll
      for (int i = 0; i < 8; i++) a[i] = As[ty * 8 + i][kk];
#pragma unroll
      for (int j = 0; j < 4; j++) b[j] = Bs[tx * 4 + j][kk];
#pragma unroll
      for (int i = 0; i < 8; i++)
#pragma unroll
        for (int j = 0; j < 4; j++)
          acc[i][j] = fmaf(a[i], b[j], acc[i][j]);
    }
    __syncthreads();
  }
#pragma unroll
  for (int i = 0; i < 8; i++) {
    int gr = bm + ty * 8 + i;
    if (gr >= M) continue;
#pragma unroll
    for (int j = 0; j < 4; j++) {
      int gc = bn + tx * 4 + j;
      if (gc < N) C[(size_t)gr * N + gc] = acc[i][j] + bias[gc];
    }
  }
}

// ---------------------------------------------------------------------------
// LayerNorm: one block (256 threads) per row.
// ---------------------------------------------------------------------------
__device__ __forceinline__ float block_sum(float v, float* sbuf) {
#pragma unroll
  for (int off = 32; off > 0; off >>= 1) v += __shfl_down(v, off, 64);
  int wid = threadIdx.x >> 6;
  __syncthreads();
  if ((threadIdx.x & 63) == 0) sbuf[wid] = v;
  __syncthreads();
  return sbuf[0] + sbuf[1] + sbuf[2] + sbuf[3];
}

__global__ __launch_bounds__(256) void ln_kernel(
    const float* __restrict__ in, int istride,
    float* __restrict__ out, int ostride,
    const float* __restrict__ g, const float* __restrict__ bta, int D)
{
  __shared__ float sbuf[4];
  size_t row = blockIdx.x;
  const float* xr = in + row * istride;
  float s = 0.f;
  for (int i = threadIdx.x; i < D; i += 256) s += xr[i];
  float mu = block_sum(s, sbuf) / (float)D;
  float v = 0.f;
  for (int i = threadIdx.x; i < D; i += 256) { float d = xr[i] - mu; v += d * d; }
  float var = block_sum(v, sbuf) / (float)D;
  float rstd = rsqrtf(var + 1e-5f);
  float* orow = out + row * ostride;
  for (int i = threadIdx.x; i < D; i += 256)
    orow[i] = (xr[i] - mu) * rstd * g[i] + bta[i];
}

// ---------------------------------------------------------------------------
// q_full[b,h,t,d] from q_lin[b,t,h*128+d]; rotary on d in [64,128) with
// angle = h * 10000^(-j/32)  (reference quirk: position axis = head index).
// ---------------------------------------------------------------------------
__global__ __launch_bounds__(256) void build_qfull(
    const float* __restrict__ q_lin, float* __restrict__ qf)
{
  size_t idx = (size_t)blockIdx.x * 256 + threadIdx.x;  // = ((b*16+h)*2048+t)*128+d
  int d = (int)(idx & 127);
  size_t r = idx >> 7;
  int t = (int)(r & 2047);
  int h = (int)((r >> 11) & 15);
  int b = (int)(r >> 15);
  const float* src = q_lin + ((size_t)(b * T_SEQ + t) * DM) + h * 128;
  float val;
  if (d < 64) {
    val = src[d];
  } else {
    int j = d & 31;
    float freq = powf(10000.0f, -(float)j / 32.0f);
    float ang = (float)h * freq;
    float c = cosf(ang), sn = sinf(ang);
    float x1 = src[64 + j], x2 = src[96 + j];
    val = (d < 96) ? (x1 * c + x2 * sn) : (x2 * c - x1 * sn);
  }
  qf[idx] = val;
}

// ---------------------------------------------------------------------------
// Flash-style causal attention. Block = (qt, h, b), 256 threads, Q tile = 64.
// K_full: d<64 from kv[...,h*192+d], d>=64 from c_kv[...,1024+(d-64)] (k rotary
// is the identity in the reference). V = kv[...,h*192+64+c].
// Thread (ty,tx): S rows ty*4+i, S cols / O cols tx+16*j.
// ---------------------------------------------------------------------------
__global__ __launch_bounds__(256) void attn_kernel(
    const float* __restrict__ qf, const float* __restrict__ kv,
    const float* __restrict__ ckv, float* __restrict__ y)
{
  __shared__ float Qs[64][33];
  __shared__ float Ks[64][33];
  __shared__ float Ps[64][65];
  __shared__ float Vs[32][129];
  int qt = blockIdx.x, h = blockIdx.y, b = blockIdx.z;
  int tid = threadIdx.x, tx = tid & 15, ty = tid >> 4;
  float acc[4][8];
  float m_i[4], l_i[4];
#pragma unroll
  for (int i = 0; i < 4; i++) {
    m_i[i] = -3.0e38f; l_i[i] = 0.f;
#pragma unroll
    for (int j = 0; j < 8; j++) acc[i][j] = 0.f;
  }
  const float scale = 0.08838834764831845f;  // 1/sqrt(128)
  const float* qbase = qf + ((size_t)((b * NH + h) * T_SEQ) + (size_t)qt * 64) * 128;

  for (int kt = 0; kt <= qt; ++kt) {
    float s[4][4];
#pragma unroll
    for (int i = 0; i < 4; i++)
#pragma unroll
      for (int j = 0; j < 4; j++) s[i][j] = 0.f;

    for (int dc = 0; dc < 4; ++dc) {
      int d0 = dc * 32;
      for (int idx = tid; idx < 64 * 32; idx += 256) {
        int m = idx >> 5, dd = idx & 31;
        Qs[m][dd] = qbase[(size_t)m * 128 + d0 + dd];
      }
      for (int idx = tid; idx < 64 * 32; idx += 256) {
        int n = idx >> 5, dd = idx & 31;
        int tg = kt * 64 + n;
        int d = d0 + dd;
        float kval;
        if (d < 64)
          kval = kv[(size_t)(b * T_SEQ + tg) * DUKV + h * 192 + d];
        else
          kval = ckv[(size_t)(b * T_SEQ + tg) * DCKV + 1024 + (d - 64)];
        Ks[n][dd] = kval;
      }
      __syncthreads();
#pragma unroll
      for (int dd = 0; dd < 32; ++dd) {
        float a[4], bb2[4];
#pragma unroll
        for (int i = 0; i < 4; i++) a[i] = Qs[ty * 4 + i][dd];
#pragma unroll
        for (int j = 0; j < 4; j++) bb2[j] = Ks[tx + 16 * j][dd];
#pragma unroll
        for (int i = 0; i < 4; i++)
#pragma unroll
          for (int j = 0; j < 4; j++)
            s[i][j] = fmaf(a[i], bb2[j], s[i][j]);
      }
      __syncthreads();
    }

    // scale + causal mask + online softmax
#pragma unroll
    for (int i = 0; i < 4; i++) {
      int qr = qt * 64 + ty * 4 + i;
      float rmax = -3.0e38f;
#pragma unroll
      for (int j = 0; j < 4; j++) {
        int kc = kt * 64 + tx + 16 * j;
        s[i][j] = (kc <= qr) ? s[i][j] * scale : -3.0e38f;
        rmax = fmaxf(rmax, s[i][j]);
      }
#pragma unroll
      for (int off = 1; off < 16; off <<= 1)
        rmax = fmaxf(rmax, __shfl_xor(rmax, off, 64));
      float mnew = fmaxf(m_i[i], rmax);
      float alpha = expf(m_i[i] - mnew);
      m_i[i] = mnew;
      float rsum = 0.f;
#pragma unroll
      for (int j = 0; j < 4; j++) {
        float p = expf(s[i][j] - mnew);
        Ps[ty * 4 + i][tx + 16 * j] = p;
        rsum += p;
      }
#pragma unroll
      for (int off = 1; off < 16; off <<= 1)
        rsum += __shfl_xor(rsum, off, 64);
      l_i[i] = l_i[i] * alpha + rsum;
#pragma unroll
      for (int j = 0; j < 8; j++) acc[i][j] *= alpha;
    }
    __syncthreads();

    // P @ V
    for (int nc = 0; nc < 2; ++nc) {
      for (int idx = tid; idx < 32 * 128; idx += 256) {
        int nn = idx >> 7, c = idx & 127;
        int tg = kt * 64 + nc * 32 + nn;
        Vs[nn][c] = kv[(size_t)(b * T_SEQ + tg) * DUKV + h * 192 + 64 + c];
      }
      __syncthreads();
#pragma unroll 8
      for (int nn = 0; nn < 32; ++nn) {
        int n = nc * 32 + nn;
        float p[4], v[8];
#pragma unroll
        for (int i = 0; i < 4; i++) p[i] = Ps[ty * 4 + i][n];
#pragma unroll
        for (int j = 0; j < 8; j++) v[j] = Vs[nn][tx + 16 * j];
#pragma unroll
        for (int i = 0; i < 4; i++)
#pragma unroll
          for (int j = 0; j < 8; j++)
            acc[i][j] = fmaf(p[i], v[j], acc[i][j]);
      }
      __syncthreads();
    }
  }

  // epilogue: y[b, t, h*128 + c]
#pragma unroll
  for (int i = 0; i < 4; i++) {
    int t = qt * 64 + ty * 4 + i;
    float inv = 1.0f / l_i[i];
#pragma unroll
    for (int j = 0; j < 8; j++)
      y[(size_t)(b * T_SEQ + t) * DM + h * 128 + tx + 16 * j] = acc[i][j] * inv;
  }
}

// ---------------------------------------------------------------------------
extern "C" void kernel_launch(void* const* d_in, const int* in_sizes, int n_in,
                              void* d_out, int out_size, void* d_ws, size_t ws_size,
                              hipStream_t stream) {
  const float* x      = (const float*)d_in[0];
  const float* Wdq_w  = (const float*)d_in[1];
  const float* Wdq_b  = (const float*)d_in[2];
  const float* qn_g   = (const float*)d_in[3];
  const float* qn_b   = (const float*)d_in[4];
  const float* Wuq_w  = (const float*)d_in[5];
  const float* Wuq_b  = (const float*)d_in[6];
  const float* Wdkv_w = (const float*)d_in[7];
  const float* Wdkv_b = (const float*)d_in[8];
  const float* kvn_g  = (const float*)d_in[9];
  const float* kvn_b  = (const float*)d_in[10];
  const float* Wukv_w = (const float*)d_in[11];
  const float* Wukv_b = (const float*)d_in[12];
  const float* Wo_w   = (const float*)d_in[13];
  const float* Wo_b   = (const float*)d_in[14];
  float* out = (float*)d_out;

  float* ws     = (float*)d_ws;
  float* c_q    = ws;                      // 4096*682   = 2,793,472
  float* q_lin  = c_q   + 2793472;         // 4096*2048  = 8,388,608 (reused as y)
  float* q_full = q_lin + 8388608;         // 2*16*2048*128 = 8,388,608
  float* c_kv   = q_full + 8388608;        // 4096*1088  = 4,456,448
  float* kv_n   = c_kv  + 4456448;         // 4096*1024  = 4,194,304
  float* kv     = kv_n  + 4194304;         // 4096*3072  = 12,582,912
  float* y      = q_lin;                   // alias: q_lin dead after build_qfull

  dim3 blk(256);

  // 1. c_q = x @ Wdq^T + b          (M=4096, N=682, K=2048)
  gemm_bt<<<dim3((DQ + 63) / 64, TOK / 128), blk, 0, stream>>>(
      x, Wdq_w, Wdq_b, c_q, TOK, DQ, DM);
  // 2. LayerNorm(c_q) in-place
  ln_kernel<<<TOK, blk, 0, stream>>>(c_q, DQ, c_q, DQ, qn_g, qn_b, DQ);
  // 3. q_lin = c_q @ Wuq^T + b      (N=2048, K=682)
  gemm_bt<<<dim3(DM / 64, TOK / 128), blk, 0, stream>>>(
      c_q, Wuq_w, Wuq_b, q_lin, TOK, DM, DQ);
  // 4. c_kv = x @ Wdkv^T + b        (N=1088, K=2048)
  gemm_bt<<<dim3(DCKV / 64, TOK / 128), blk, 0, stream>>>(
      x, Wdkv_w, Wdkv_b, c_kv, TOK, DCKV, DM);
  // 5. kv_n = LayerNorm(c_kv[:, :1024])
  ln_kernel<<<TOK, blk, 0, stream>>>(c_kv, DCKV, kv_n, DKV, kvn_g, kvn_b, DKV);
  // 6. kv = kv_n @ Wukv^T + b       (N=3072, K=1024)
  gemm_bt<<<dim3(DUKV / 64, TOK / 128), blk, 0, stream>>>(
      kv_n, Wukv_w, Wukv_b, kv, TOK, DUKV, DKV);
  // 7. q_full (rotary by head index)
  build_qfull<<<(2 * NH * T_SEQ * 128) / 256, blk, 0, stream>>>(q_lin, q_full);
  // 8. attention -> y[b,t,h*128+d]
  attn_kernel<<<dim3(T_SEQ / 64, NH, 2), blk, 0, stream>>>(q_full, kv, c_kv, y);
  // 9. out = y @ Wo^T + b           (N=2048, K=2048)
  gemm_bt<<<dim3(DM / 64, TOK / 128), blk, 0, stream>>>(
      y, Wo_w, Wo_b, out, TOK, DM, DM);
}

// Round 3
// 2321.077 us; speedup vs baseline: 2.6572x; 2.6572x over previous
//
#include <hip/hip_runtime.h>
#include <math.h>

#define TOK 4096
#define DM 2048
#define DQ 682
#define DQP 704      // DQ padded to mult of 32 (K pad)
#define DCKV 1088
#define DKV 1024
#define DUKV 3072
#define NH 16
#define T_SEQ 2048

typedef __attribute__((ext_vector_type(8))) short short8;
typedef __attribute__((ext_vector_type(4))) float floatx4;

__device__ __forceinline__ unsigned short f2bf(float f) {
  union { float f; unsigned int u; } v; v.f = f;
  unsigned int u = v.u;
  u += 0x7fffu + ((u >> 16) & 1u);
  return (unsigned short)(u >> 16);
}

typedef __attribute__((address_space(1))) const unsigned int as1_u32;
typedef __attribute__((address_space(3))) unsigned int as3_u32;
__device__ __forceinline__ void async16(const void* g, void* l) {
  __builtin_amdgcn_global_load_lds((as1_u32*)g, (as3_u32*)l, 16, 0, 0);
}

// ---------------------------------------------------------------------------
// bf16 MFMA GEMM (m97 structure): C[M,N]fp32 = A[M,K]bf16 * B[N,K]bf16^T + bias
// 128x128 tile, BK=32, 256 threads (4 waves, 2x2), 4x4 mfma_f32_16x16x32_bf16
// per wave. A,B staged via global_load_lds width=16. Caller guarantees the
// staged ranges (M pad 128 / N pad 128 / K pad 32) are valid memory; epilogue
// masks columns >= Nvalid.
// ---------------------------------------------------------------------------
__global__ __launch_bounds__(256) void gemm_bf16(
    const unsigned short* __restrict__ A, int lda,
    const unsigned short* __restrict__ B, int ldb,
    const float* __restrict__ bias, float* __restrict__ C, int ldc,
    int Nvalid, int K)
{
  __shared__ __align__(16) unsigned short As[128 * 32];
  __shared__ __align__(16) unsigned short Bs[128 * 32];
  const int tid = threadIdx.x;
  const int w = tid >> 6;       // wave 0..3
  const int lane = tid & 63;
  const int q = lane >> 4;      // quad 0..3
  const int r = lane & 15;
  const int bm = blockIdx.y * 128;
  const int bn = blockIdx.x * 128;

  floatx4 acc[4][4];
#pragma unroll
  for (int i = 0; i < 4; i++)
#pragma unroll
    for (int j = 0; j < 4; j++) acc[i][j] = (floatx4){0.f, 0.f, 0.f, 0.f};

  // staging: thread t loads 16B: row = t>>2 (+64 for 2nd issue), col = (t&3)*8
  const int srow = tid >> 2;
  const int scol = (tid & 3) * 8;
  const unsigned short* Ag0 = A + (size_t)(bm + srow) * lda + scol;
  const unsigned short* Ag1 = A + (size_t)(bm + 64 + srow) * lda + scol;
  const unsigned short* Bg0 = B + (size_t)(bn + srow) * ldb + scol;
  const unsigned short* Bg1 = B + (size_t)(bn + 64 + srow) * ldb + scol;
  // wave-uniform LDS bases (HW adds lane*16B)
  unsigned short* AsL0 = &As[w * 512];
  unsigned short* AsL1 = &As[2048 + w * 512];
  unsigned short* BsL0 = &Bs[w * 512];
  unsigned short* BsL1 = &Bs[2048 + w * 512];

  // wave's sub-tile origin: rows (w>>1)*64, cols (w&1)*64
  const int mrow0 = (w >> 1) * 64;
  const int ncol0 = (w & 1) * 64;

  for (int k0 = 0; k0 < K; k0 += 32) {
    async16(Ag0 + k0, AsL0);
    async16(Ag1 + k0, AsL1);
    async16(Bg0 + k0, BsL0);
    async16(Bg1 + k0, BsL1);
    __syncthreads();   // compiler drains vmcnt before barrier
    short8 a[4], b[4];
#pragma unroll
    for (int i = 0; i < 4; i++)
      a[i] = *(const short8*)&As[(mrow0 + i * 16 + r) * 32 + q * 8];
#pragma unroll
    for (int j = 0; j < 4; j++)
      b[j] = *(const short8*)&Bs[(ncol0 + j * 16 + r) * 32 + q * 8];
#pragma unroll
    for (int i = 0; i < 4; i++)
#pragma unroll
      for (int j = 0; j < 4; j++)
        acc[i][j] = __builtin_amdgcn_mfma_f32_16x16x32_bf16(a[i], b[j], acc[i][j], 0, 0, 0);
    __syncthreads();
  }

  // epilogue: C/D layout col=lane&15, row=quad*4+v  (m89-verified)
#pragma unroll
  for (int j = 0; j < 4; j++) {
    int gc = bn + ncol0 + j * 16 + r;
    if (gc >= Nvalid) continue;
    float bv = bias[gc];
#pragma unroll
    for (int i = 0; i < 4; i++) {
#pragma unroll
      for (int v = 0; v < 4; v++) {
        int gr = bm + mrow0 + i * 16 + q * 4 + v;
        C[(size_t)gr * ldc + gc] = acc[i][j][v] + bv;
      }
    }
  }
}

// ---------------------------------------------------------------------------
// fp32 -> bf16 convert with zero padding. out has orows*ocols elements
// (total); in is irows x icols row-major.
// ---------------------------------------------------------------------------
__global__ __launch_bounds__(256) void cvt_bf16_pad(
    const float* __restrict__ in, unsigned short* __restrict__ out,
    int irows, int icols, int ocols, long total)
{
  long idx = (long)blockIdx.x * 256 + threadIdx.x;
  if (idx >= total) return;
  int rr = (int)(idx / ocols);
  int cc = (int)(idx - (long)rr * ocols);
  out[idx] = (rr < irows && cc < icols) ? f2bf(in[(size_t)rr * icols + cc]) : 0;
}

// ---------------------------------------------------------------------------
// LayerNorm fp32 in -> bf16 out (zero-padded to ocols). One block per row.
// ---------------------------------------------------------------------------
__device__ __forceinline__ float block_sum(float v, float* sbuf) {
#pragma unroll
  for (int off = 32; off > 0; off >>= 1) v += __shfl_down(v, off, 64);
  int wid = threadIdx.x >> 6;
  __syncthreads();
  if ((threadIdx.x & 63) == 0) sbuf[wid] = v;
  __syncthreads();
  return sbuf[0] + sbuf[1] + sbuf[2] + sbuf[3];
}

__global__ __launch_bounds__(256) void ln_bf16_kernel(
    const float* __restrict__ in, int istride,
    unsigned short* __restrict__ out, int ocols,
    const float* __restrict__ g, const float* __restrict__ bta, int D)
{
  __shared__ float sbuf[4];
  size_t row = blockIdx.x;
  const float* xr = in + row * istride;
  float s = 0.f;
  for (int i = threadIdx.x; i < D; i += 256) s += xr[i];
  float mu = block_sum(s, sbuf) / (float)D;
  float v = 0.f;
  for (int i = threadIdx.x; i < D; i += 256) { float d = xr[i] - mu; v += d * d; }
  float var = block_sum(v, sbuf) / (float)D;
  float rstd = rsqrtf(var + 1e-5f);
  unsigned short* orow = out + row * ocols;
  for (int i = threadIdx.x; i < ocols; i += 256)
    orow[i] = (i < D) ? f2bf((xr[i] - mu) * rstd * g[i] + bta[i]) : 0;
}

// ---------------------------------------------------------------------------
// q_full[b,h,t,d] from q_lin[b,t,h*128+d]; rotary angle = h * 10000^(-j/32)
// (reference quirk: position axis = head index for q).
// ---------------------------------------------------------------------------
__global__ __launch_bounds__(256) void build_qfull(
    const float* __restrict__ q_lin, float* __restrict__ qf)
{
  size_t idx = (size_t)blockIdx.x * 256 + threadIdx.x;
  int d = (int)(idx & 127);
  size_t rr = idx >> 7;
  int t = (int)(rr & 2047);
  int h = (int)((rr >> 11) & 15);
  int b = (int)(rr >> 15);
  const float* src = q_lin + ((size_t)(b * T_SEQ + t) * DM) + h * 128;
  float val;
  if (d < 64) {
    val = src[d];
  } else {
    int j = d & 31;
    float freq = powf(10000.0f, -(float)j / 32.0f);
    float ang = (float)h * freq;
    float c = cosf(ang), sn = sinf(ang);
    float x1 = src[64 + j], x2 = src[96 + j];
    val = (d < 96) ? (x1 * c + x2 * sn) : (x2 * c - x1 * sn);
  }
  qf[idx] = val;
}

// ---------------------------------------------------------------------------
// Flash-style causal attention (fp32, unchanged structure); y output -> bf16.
// k rotary is identity in the reference; K_full d>=64 comes straight from
// c_kv[..., 1024+].
// ---------------------------------------------------------------------------
__global__ __launch_bounds__(256) void attn_kernel(
    const float* __restrict__ qf, const float* __restrict__ kv,
    const float* __restrict__ ckv, unsigned short* __restrict__ y)
{
  __shared__ float Qs[64][33];
  __shared__ float Ks[64][33];
  __shared__ float Ps[64][65];
  __shared__ float Vs[32][129];
  int qt = blockIdx.x, h = blockIdx.y, b = blockIdx.z;
  int tid = threadIdx.x, tx = tid & 15, ty = tid >> 4;
  float acc[4][8];
  float m_i[4], l_i[4];
#pragma unroll
  for (int i = 0; i < 4; i++) {
    m_i[i] = -3.0e38f; l_i[i] = 0.f;
#pragma unroll
    for (int j = 0; j < 8; j++) acc[i][j] = 0.f;
  }
  const float scale = 0.08838834764831845f;
  const float* qbase = qf + ((size_t)((b * NH + h) * T_SEQ) + (size_t)qt * 64) * 128;

  for (int kt = 0; kt <= qt; ++kt) {
    float s[4][4];
#pragma unroll
    for (int i = 0; i < 4; i++)
#pragma unroll
      for (int j = 0; j < 4; j++) s[i][j] = 0.f;

    for (int dc = 0; dc < 4; ++dc) {
      int d0 = dc * 32;
      for (int idx = tid; idx < 64 * 32; idx += 256) {
        int m = idx >> 5, dd = idx & 31;
        Qs[m][dd] = qbase[(size_t)m * 128 + d0 + dd];
      }
      for (int idx = tid; idx < 64 * 32; idx += 256) {
        int n = idx >> 5, dd = idx & 31;
        int tg = kt * 64 + n;
        int d = d0 + dd;
        float kval;
        if (d < 64)
          kval = kv[(size_t)(b * T_SEQ + tg) * DUKV + h * 192 + d];
        else
          kval = ckv[(size_t)(b * T_SEQ + tg) * DCKV + 1024 + (d - 64)];
        Ks[n][dd] = kval;
      }
      __syncthreads();
#pragma unroll
      for (int dd = 0; dd < 32; ++dd) {
        float a[4], bb2[4];
#pragma unroll
        for (int i = 0; i < 4; i++) a[i] = Qs[ty * 4 + i][dd];
#pragma unroll
        for (int j = 0; j < 4; j++) bb2[j] = Ks[tx + 16 * j][dd];
#pragma unroll
        for (int i = 0; i < 4; i++)
#pragma unroll
          for (int j = 0; j < 4; j++)
            s[i][j] = fmaf(a[i], bb2[j], s[i][j]);
      }
      __syncthreads();
    }

#pragma unroll
    for (int i = 0; i < 4; i++) {
      int qr = qt * 64 + ty * 4 + i;
      float rmax = -3.0e38f;
#pragma unroll
      for (int j = 0; j < 4; j++) {
        int kc = kt * 64 + tx + 16 * j;
        s[i][j] = (kc <= qr) ? s[i][j] * scale : -3.0e38f;
        rmax = fmaxf(rmax, s[i][j]);
      }
#pragma unroll
      for (int off = 1; off < 16; off <<= 1)
        rmax = fmaxf(rmax, __shfl_xor(rmax, off, 64));
      float mnew = fmaxf(m_i[i], rmax);
      float alpha = expf(m_i[i] - mnew);
      m_i[i] = mnew;
      float rsum = 0.f;
#pragma unroll
      for (int j = 0; j < 4; j++) {
        float p = expf(s[i][j] - mnew);
        Ps[ty * 4 + i][tx + 16 * j] = p;
        rsum += p;
      }
#pragma unroll
      for (int off = 1; off < 16; off <<= 1)
        rsum += __shfl_xor(rsum, off, 64);
      l_i[i] = l_i[i] * alpha + rsum;
#pragma unroll
      for (int j = 0; j < 8; j++) acc[i][j] *= alpha;
    }
    __syncthreads();

    for (int nc = 0; nc < 2; ++nc) {
      for (int idx = tid; idx < 32 * 128; idx += 256) {
        int nn = idx >> 7, c = idx & 127;
        int tg = kt * 64 + nc * 32 + nn;
        Vs[nn][c] = kv[(size_t)(b * T_SEQ + tg) * DUKV + h * 192 + 64 + c];
      }
      __syncthreads();
#pragma unroll 8
      for (int nn = 0; nn < 32; ++nn) {
        int n = nc * 32 + nn;
        float p[4], v[8];
#pragma unroll
        for (int i = 0; i < 4; i++) p[i] = Ps[ty * 4 + i][n];
#pragma unroll
        for (int j = 0; j < 8; j++) v[j] = Vs[nn][tx + 16 * j];
#pragma unroll
        for (int i = 0; i < 4; i++)
#pragma unroll
          for (int j = 0; j < 8; j++)
            acc[i][j] = fmaf(p[i], v[j], acc[i][j]);
      }
      __syncthreads();
    }
  }

#pragma unroll
  for (int i = 0; i < 4; i++) {
    int t = qt * 64 + ty * 4 + i;
    float inv = 1.0f / l_i[i];
#pragma unroll
    for (int j = 0; j < 8; j++)
      y[(size_t)(b * T_SEQ + t) * DM + h * 128 + tx + 16 * j] = f2bf(acc[i][j] * inv);
  }
}

// ---------------------------------------------------------------------------
extern "C" void kernel_launch(void* const* d_in, const int* in_sizes, int n_in,
                              void* d_out, int out_size, void* d_ws, size_t ws_size,
                              hipStream_t stream) {
  const float* x      = (const float*)d_in[0];
  const float* Wdq_w  = (const float*)d_in[1];
  const float* Wdq_b  = (const float*)d_in[2];
  const float* qn_g   = (const float*)d_in[3];
  const float* qn_b   = (const float*)d_in[4];
  const float* Wuq_w  = (const float*)d_in[5];
  const float* Wuq_b  = (const float*)d_in[6];
  const float* Wdkv_w = (const float*)d_in[7];
  const float* Wdkv_b = (const float*)d_in[8];
  const float* kvn_g  = (const float*)d_in[9];
  const float* kvn_b  = (const float*)d_in[10];
  const float* Wukv_w = (const float*)d_in[11];
  const float* Wukv_b = (const float*)d_in[12];
  const float* Wo_w   = (const float*)d_in[13];
  const float* Wo_b   = (const float*)d_in[14];
  float* out = (float*)d_out;

  float* ws = (float*)d_ws;
  // region A (also q_full alias): x_bf16 + 4 padded bf16 weights
  unsigned short* x_bf   = (unsigned short*)(ws);             // 4096x2048
  unsigned short* Wdq_bf = (unsigned short*)(ws + 4194304);   // 768x2048
  unsigned short* Wuq_bf = (unsigned short*)(ws + 4980736);   // 2048x704
  unsigned short* Wdkv_bf= (unsigned short*)(ws + 5701632);   // 1152x2048
  unsigned short* Wukv_bf= (unsigned short*)(ws + 6881280);   // 3072x1024 (ends 8454144)
  float* q_full = ws;                                         // alias, 8388608 f
  float* c_q    = ws + 8454144;                               // 4096x682 fp32
  unsigned short* c_q_bf = (unsigned short*)(ws + 11247616);  // 4096x704
  float* q_lin  = ws + 12689408;                              // 4096x2048 fp32
  unsigned short* Wo_bf  = (unsigned short*)(ws + 12689408);  // alias, 2048x2048
  unsigned short* y_bf   = (unsigned short*)(ws + 14786560);  // alias, 4096x2048
  float* c_kv   = ws + 21078016;                              // 4096x1088 fp32
  unsigned short* kvn_bf = (unsigned short*)(ws + 25534464);  // 4096x1024
  float* kv     = ws + 27631616;                              // 4096x3072 fp32

  dim3 blk(256);

  // fp32 -> bf16 conversions (padded)
  cvt_bf16_pad<<<(4096L*2048 + 255) / 256, blk, 0, stream>>>(x, x_bf, 4096, 2048, 2048, 4096L*2048);
  cvt_bf16_pad<<<(768L*2048 + 255) / 256, blk, 0, stream>>>(Wdq_w, Wdq_bf, 682, 2048, 2048, 768L*2048);
  cvt_bf16_pad<<<(2048L*704 + 255) / 256, blk, 0, stream>>>(Wuq_w, Wuq_bf, 2048, 682, 704, 2048L*704);
  cvt_bf16_pad<<<(1152L*2048 + 255) / 256, blk, 0, stream>>>(Wdkv_w, Wdkv_bf, 1088, 2048, 2048, 1152L*2048);
  cvt_bf16_pad<<<(3072L*1024 + 255) / 256, blk, 0, stream>>>(Wukv_w, Wukv_bf, 3072, 1024, 1024, 3072L*1024);

  // 1. c_q = x @ Wdq^T + b   (N=682, padded weight rows to 768)
  gemm_bf16<<<dim3(6, 32), blk, 0, stream>>>(x_bf, 2048, Wdq_bf, 2048, Wdq_b, c_q, DQ, DQ, 2048);
  // 2. LN(c_q) -> c_q_bf [4096][704] zero-padded K
  ln_bf16_kernel<<<TOK, blk, 0, stream>>>(c_q, DQ, c_q_bf, DQP, qn_g, qn_b, DQ);
  // 3. q_lin = c_q @ Wuq^T + b   (K=704 padded)
  gemm_bf16<<<dim3(16, 32), blk, 0, stream>>>(c_q_bf, DQP, Wuq_bf, DQP, Wuq_b, q_lin, DM, DM, DQP);
  // 4. c_kv = x @ Wdkv^T + b  (N=1088, padded weight rows to 1152)
  gemm_bf16<<<dim3(9, 32), blk, 0, stream>>>(x_bf, 2048, Wdkv_bf, 2048, Wdkv_b, c_kv, DCKV, DCKV, 2048);
  // 5. kv_n = LN(c_kv[:, :1024]) -> bf16
  ln_bf16_kernel<<<TOK, blk, 0, stream>>>(c_kv, DCKV, kvn_bf, DKV, kvn_g, kvn_b, DKV);
  // 6. kv = kv_n @ Wukv^T + b
  gemm_bf16<<<dim3(24, 32), blk, 0, stream>>>(kvn_bf, DKV, Wukv_bf, DKV, Wukv_b, kv, DUKV, DUKV, DKV);
  // 7. q_full (rotary by head index); q_lin dead after this
  build_qfull<<<(2 * NH * T_SEQ * 128) / 256, blk, 0, stream>>>(q_lin, q_full);
  // 8. Wo -> bf16 (into dead q_lin region)
  cvt_bf16_pad<<<(2048L*2048 + 255) / 256, blk, 0, stream>>>(Wo_w, Wo_bf, 2048, 2048, 2048, 2048L*2048);
  // 9. attention -> y_bf [b,t,h*128+d] (bf16)
  attn_kernel<<<dim3(T_SEQ / 64, NH, 2), blk, 0, stream>>>(q_full, kv, c_kv, y_bf);
  // 10. out = y @ Wo^T + b
  gemm_bf16<<<dim3(16, 32), blk, 0, stream>>>(y_bf, 2048, Wo_bf, 2048, Wo_b, out, DM, DM, 2048);
}

// Round 4
// 793.537 us; speedup vs baseline: 7.7722x; 2.9250x over previous
//
#include <hip/hip_runtime.h>
#include <math.h>

#define TOK 4096
#define DM 2048
#define DQ 682
#define DQP 704
#define DCKV 1088
#define DKV 1024
#define DUKV 3072
#define NH 16
#define T_SEQ 2048

typedef __attribute__((ext_vector_type(8))) short short8;
typedef __attribute__((ext_vector_type(4))) float floatx4;
typedef unsigned short ushort_t;

__device__ __forceinline__ unsigned short f2bf(float f) {
  union { float f; unsigned int u; } v; v.f = f;
  unsigned int u = v.u;
  u += 0x7fffu + ((u >> 16) & 1u);
  return (unsigned short)(u >> 16);
}
// cheap round (positive values, e.g. softmax P in [0,1])
__device__ __forceinline__ unsigned short f2bf_fast(float f) {
  union { float f; unsigned int u; } v; v.f = f;
  return (unsigned short)((v.u + 0x8000u) >> 16);
}

typedef __attribute__((address_space(1))) const unsigned int as1_u32;
typedef __attribute__((address_space(3))) unsigned int as3_u32;
__device__ __forceinline__ void async16(const void* g, void* l) {
  __builtin_amdgcn_global_load_lds((as1_u32*)g, (as3_u32*)l, 16, 0, 0);
}

// ---------------------------------------------------------------------------
// bf16 MFMA GEMM (m97 structure), fp32 output.
// ---------------------------------------------------------------------------
__global__ __launch_bounds__(256) void gemm_bf16(
    const unsigned short* __restrict__ A, int lda,
    const unsigned short* __restrict__ B, int ldb,
    const float* __restrict__ bias, float* __restrict__ C, int ldc,
    int Nvalid, int K)
{
  __shared__ __align__(16) unsigned short As[128 * 32];
  __shared__ __align__(16) unsigned short Bs[128 * 32];
  const int tid = threadIdx.x;
  const int w = tid >> 6;
  const int lane = tid & 63;
  const int q = lane >> 4;
  const int r = lane & 15;
  const int bm = blockIdx.y * 128;
  const int bn = blockIdx.x * 128;

  floatx4 acc[4][4];
#pragma unroll
  for (int i = 0; i < 4; i++)
#pragma unroll
    for (int j = 0; j < 4; j++) acc[i][j] = (floatx4){0.f, 0.f, 0.f, 0.f};

  const int srow = tid >> 2;
  const int scol = (tid & 3) * 8;
  const unsigned short* Ag0 = A + (size_t)(bm + srow) * lda + scol;
  const unsigned short* Ag1 = A + (size_t)(bm + 64 + srow) * lda + scol;
  const unsigned short* Bg0 = B + (size_t)(bn + srow) * ldb + scol;
  const unsigned short* Bg1 = B + (size_t)(bn + 64 + srow) * ldb + scol;
  unsigned short* AsL0 = &As[w * 512];
  unsigned short* AsL1 = &As[2048 + w * 512];
  unsigned short* BsL0 = &Bs[w * 512];
  unsigned short* BsL1 = &Bs[2048 + w * 512];

  const int mrow0 = (w >> 1) * 64;
  const int ncol0 = (w & 1) * 64;

  for (int k0 = 0; k0 < K; k0 += 32) {
    async16(Ag0 + k0, AsL0);
    async16(Ag1 + k0, AsL1);
    async16(Bg0 + k0, BsL0);
    async16(Bg1 + k0, BsL1);
    __syncthreads();
    short8 a[4], b[4];
#pragma unroll
    for (int i = 0; i < 4; i++)
      a[i] = *(const short8*)&As[(mrow0 + i * 16 + r) * 32 + q * 8];
#pragma unroll
    for (int j = 0; j < 4; j++)
      b[j] = *(const short8*)&Bs[(ncol0 + j * 16 + r) * 32 + q * 8];
#pragma unroll
    for (int i = 0; i < 4; i++)
#pragma unroll
      for (int j = 0; j < 4; j++)
        acc[i][j] = __builtin_amdgcn_mfma_f32_16x16x32_bf16(a[i], b[j], acc[i][j], 0, 0, 0);
    __syncthreads();
  }

#pragma unroll
  for (int j = 0; j < 4; j++) {
    int gc = bn + ncol0 + j * 16 + r;
    if (gc >= Nvalid) continue;
    float bv = bias[gc];
#pragma unroll
    for (int i = 0; i < 4; i++) {
#pragma unroll
      for (int v = 0; v < 4; v++) {
        int gr = bm + mrow0 + i * 16 + q * 4 + v;
        C[(size_t)gr * ldc + gc] = acc[i][j][v] + bv;
      }
    }
  }
}

// ---------------------------------------------------------------------------
// Same GEMM but bf16 output (for kv).
// ---------------------------------------------------------------------------
__global__ __launch_bounds__(256) void gemm_bf16_obf(
    const unsigned short* __restrict__ A, int lda,
    const unsigned short* __restrict__ B, int ldb,
    const float* __restrict__ bias, unsigned short* __restrict__ C, int ldc,
    int Nvalid, int K)
{
  __shared__ __align__(16) unsigned short As[128 * 32];
  __shared__ __align__(16) unsigned short Bs[128 * 32];
  const int tid = threadIdx.x;
  const int w = tid >> 6;
  const int lane = tid & 63;
  const int q = lane >> 4;
  const int r = lane & 15;
  const int bm = blockIdx.y * 128;
  const int bn = blockIdx.x * 128;

  floatx4 acc[4][4];
#pragma unroll
  for (int i = 0; i < 4; i++)
#pragma unroll
    for (int j = 0; j < 4; j++) acc[i][j] = (floatx4){0.f, 0.f, 0.f, 0.f};

  const int srow = tid >> 2;
  const int scol = (tid & 3) * 8;
  const unsigned short* Ag0 = A + (size_t)(bm + srow) * lda + scol;
  const unsigned short* Ag1 = A + (size_t)(bm + 64 + srow) * lda + scol;
  const unsigned short* Bg0 = B + (size_t)(bn + srow) * ldb + scol;
  const unsigned short* Bg1 = B + (size_t)(bn + 64 + srow) * ldb + scol;
  unsigned short* AsL0 = &As[w * 512];
  unsigned short* AsL1 = &As[2048 + w * 512];
  unsigned short* BsL0 = &Bs[w * 512];
  unsigned short* BsL1 = &Bs[2048 + w * 512];

  const int mrow0 = (w >> 1) * 64;
  const int ncol0 = (w & 1) * 64;

  for (int k0 = 0; k0 < K; k0 += 32) {
    async16(Ag0 + k0, AsL0);
    async16(Ag1 + k0, AsL1);
    async16(Bg0 + k0, BsL0);
    async16(Bg1 + k0, BsL1);
    __syncthreads();
    short8 a[4], b[4];
#pragma unroll
    for (int i = 0; i < 4; i++)
      a[i] = *(const short8*)&As[(mrow0 + i * 16 + r) * 32 + q * 8];
#pragma unroll
    for (int j = 0; j < 4; j++)
      b[j] = *(const short8*)&Bs[(ncol0 + j * 16 + r) * 32 + q * 8];
#pragma unroll
    for (int i = 0; i < 4; i++)
#pragma unroll
      for (int j = 0; j < 4; j++)
        acc[i][j] = __builtin_amdgcn_mfma_f32_16x16x32_bf16(a[i], b[j], acc[i][j], 0, 0, 0);
    __syncthreads();
  }

#pragma unroll
  for (int j = 0; j < 4; j++) {
    int gc = bn + ncol0 + j * 16 + r;
    if (gc >= Nvalid) continue;
    float bv = bias[gc];
#pragma unroll
    for (int i = 0; i < 4; i++) {
#pragma unroll
      for (int v = 0; v < 4; v++) {
        int gr = bm + mrow0 + i * 16 + q * 4 + v;
        C[(size_t)gr * ldc + gc] = f2bf(acc[i][j][v] + bv);
      }
    }
  }
}

// ---------------------------------------------------------------------------
__global__ __launch_bounds__(256) void cvt_bf16_pad(
    const float* __restrict__ in, unsigned short* __restrict__ out,
    int irows, int icols, int ocols, long total)
{
  long idx = (long)blockIdx.x * 256 + threadIdx.x;
  if (idx >= total) return;
  int rr = (int)(idx / ocols);
  int cc = (int)(idx - (long)rr * ocols);
  out[idx] = (rr < irows && cc < icols) ? f2bf(in[(size_t)rr * icols + cc]) : 0;
}

// ---------------------------------------------------------------------------
__device__ __forceinline__ float block_sum(float v, float* sbuf) {
#pragma unroll
  for (int off = 32; off > 0; off >>= 1) v += __shfl_down(v, off, 64);
  int wid = threadIdx.x >> 6;
  __syncthreads();
  if ((threadIdx.x & 63) == 0) sbuf[wid] = v;
  __syncthreads();
  return sbuf[0] + sbuf[1] + sbuf[2] + sbuf[3];
}

__global__ __launch_bounds__(256) void ln_bf16_kernel(
    const float* __restrict__ in, int istride,
    unsigned short* __restrict__ out, int ocols,
    const float* __restrict__ g, const float* __restrict__ bta, int D)
{
  __shared__ float sbuf[4];
  size_t row = blockIdx.x;
  const float* xr = in + row * istride;
  float s = 0.f;
  for (int i = threadIdx.x; i < D; i += 256) s += xr[i];
  float mu = block_sum(s, sbuf) / (float)D;
  float v = 0.f;
  for (int i = threadIdx.x; i < D; i += 256) { float d = xr[i] - mu; v += d * d; }
  float var = block_sum(v, sbuf) / (float)D;
  float rstd = rsqrtf(var + 1e-5f);
  unsigned short* orow = out + row * ocols;
  for (int i = threadIdx.x; i < ocols; i += 256)
    orow[i] = (i < D) ? f2bf((xr[i] - mu) * rstd * g[i] + bta[i]) : 0;
}

// ---------------------------------------------------------------------------
// Q_all[b,h,t,128] bf16, rotary angle = h * 10000^(-j/32) (reference quirk),
// with softmax scale * log2(e) folded in.
// ---------------------------------------------------------------------------
__global__ __launch_bounds__(256) void build_qfull_bf(
    const float* __restrict__ q_lin, unsigned short* __restrict__ qf)
{
  const float QS = (float)(0.08838834764831845 * 1.4426950408889634);
  size_t idx = (size_t)blockIdx.x * 256 + threadIdx.x;
  int d = (int)(idx & 127);
  size_t rr = idx >> 7;
  int t = (int)(rr & 2047);
  int h = (int)((rr >> 11) & 15);
  int b = (int)(rr >> 15);
  const float* src = q_lin + ((size_t)(b * T_SEQ + t) * DM) + h * 128;
  float val;
  if (d < 64) {
    val = src[d];
  } else {
    int j = d & 31;
    float freq = exp2f(-(float)j * (13.287712379549449f / 32.0f));
    float ang = (float)h * freq;
    float c = cosf(ang), sn = sinf(ang);
    float x1 = src[64 + j], x2 = src[96 + j];
    val = (d < 96) ? (x1 * c + x2 * sn) : (x2 * c - x1 * sn);
  }
  qf[idx] = f2bf(val * QS);
}

// ---------------------------------------------------------------------------
// K_all[b,h,t,128] bf16: d<64 = kv_bf[..., h*192+d]; d>=64 = rope part of c_kv
// (k rotary is identity in the reference).
// ---------------------------------------------------------------------------
__global__ __launch_bounds__(256) void repack_k(
    const unsigned short* __restrict__ kv_bf, const float* __restrict__ ckv,
    unsigned short* __restrict__ K)
{
  size_t idx = (size_t)blockIdx.x * 256 + threadIdx.x;
  int d = (int)(idx & 127);
  int t = (int)((idx >> 7) & 2047);
  int h = (int)((idx >> 18) & 15);
  int b = (int)(idx >> 22);
  unsigned short val;
  if (d < 64)
    val = kv_bf[(size_t)(b * T_SEQ + t) * DUKV + h * 192 + d];
  else
    val = f2bf(ckv[(size_t)(b * T_SEQ + t) * DCKV + 1024 + (d - 64)]);
  K[idx] = val;
}

// Vt_all[b,h,d,t] bf16 = V[b,h,t,d] transposed.
__global__ __launch_bounds__(256) void repack_vt(
    const unsigned short* __restrict__ kv_bf, unsigned short* __restrict__ Vt)
{
  size_t idx = (size_t)blockIdx.x * 256 + threadIdx.x;
  int t = (int)(idx & 2047);
  int d = (int)((idx >> 11) & 127);
  int h = (int)((idx >> 18) & 15);
  int b = (int)(idx >> 22);
  Vt[idx] = kv_bf[(size_t)(b * T_SEQ + t) * DUKV + h * 192 + 64 + d];
}

// ---------------------------------------------------------------------------
// MFMA flash attention. Block = (qt 128-row Q tile, h, b), 4 waves.
// Wave w owns Q rows [w*32, w*32+32). Q frags in registers. Per 64-col K tile:
// S = Q K^T (mfma), log2-domain online softmax, P -> LDS bf16, O += P V (mfma,
// V^T tiles as B-operand). LDS strides padded (136/72 shorts) -> 2-way free.
// ---------------------------------------------------------------------------
__global__ __launch_bounds__(256) void attn_mfma(
    const unsigned short* __restrict__ Qall,
    const unsigned short* __restrict__ Kall,
    const unsigned short* __restrict__ Vtall,
    unsigned short* __restrict__ y)
{
  __shared__ __align__(16) unsigned short sm[27136];   // 54,272 B
  unsigned short* Ks  = sm;            // [64][136]
  unsigned short* Vts = sm + 8704;     // [128][72]
  unsigned short* Ps  = sm + 17920;    // [128][72]
  const int qt = (int)gridDim.x - 1 - (int)blockIdx.x;  // heavy blocks first
  const int h = blockIdx.y, b = blockIdx.z;
  const int tid = threadIdx.x;
  const int w = tid >> 6, lane = tid & 63, q = lane >> 4, r = lane & 15;
  const size_t bh = (size_t)(b * NH + h);
  const unsigned short* Qbase = Qall + (bh * T_SEQ + (size_t)qt * 128) * 128;
  const unsigned short* Kbase = Kall + bh * T_SEQ * 128;
  const unsigned short* Vtbase = Vtall + bh * 128 * T_SEQ;

  // stage Q tile (128x128) into sm (stride 136), then load fragments to regs
  {
    const int row = tid >> 1, ch = (tid & 1) * 64;
    const unsigned short* g = Qbase + row * 128 + ch;
    short8 tmp[8];
#pragma unroll
    for (int c8 = 0; c8 < 8; c8++) tmp[c8] = *(const short8*)(g + c8 * 8);
#pragma unroll
    for (int c8 = 0; c8 < 8; c8++)
      *(short8*)&sm[row * 136 + ch + c8 * 8] = tmp[c8];
  }
  __syncthreads();
  short8 qa[2][4];
#pragma unroll
  for (int i = 0; i < 2; i++)
#pragma unroll
    for (int c = 0; c < 4; c++)
      qa[i][c] = *(const short8*)&sm[(w * 32 + i * 16 + r) * 136 + c * 32 + q * 8];
  __syncthreads();

  floatx4 oacc[2][8];
#pragma unroll
  for (int i = 0; i < 2; i++)
#pragma unroll
    for (int jd = 0; jd < 8; jd++) oacc[i][jd] = (floatx4){0.f, 0.f, 0.f, 0.f};
  float m_i[2][4], l_i[2][4];
#pragma unroll
  for (int i = 0; i < 2; i++)
#pragma unroll
    for (int v = 0; v < 4; v++) { m_i[i][v] = -3.0e38f; l_i[i][v] = 0.f; }

  const int ktmax = 2 * qt + 1;
  for (int kt = 0; kt <= ktmax; kt++) {
    // stage K tile [64][128] -> Ks stride 136
    {
      const int row = tid >> 2, cq = (tid & 3) * 32;
      const unsigned short* g = Kbase + (size_t)(kt * 64 + row) * 128 + cq;
      short8 tmp[4];
#pragma unroll
      for (int c8 = 0; c8 < 4; c8++) tmp[c8] = *(const short8*)(g + c8 * 8);
#pragma unroll
      for (int c8 = 0; c8 < 4; c8++)
        *(short8*)&Ks[row * 136 + cq + c8 * 8] = tmp[c8];
    }
    // stage V^T tile [128][64] -> Vts stride 72
    {
      const int d = tid >> 1, ch = (tid & 1) * 32;
      const unsigned short* g = Vtbase + (size_t)d * T_SEQ + kt * 64 + ch;
      short8 tmp[4];
#pragma unroll
      for (int c8 = 0; c8 < 4; c8++) tmp[c8] = *(const short8*)(g + c8 * 8);
#pragma unroll
      for (int c8 = 0; c8 < 4; c8++)
        *(short8*)&Vts[d * 72 + ch + c8 * 8] = tmp[c8];
    }
    __syncthreads();

    const bool active = (kt * 64 <= qt * 128 + w * 32 + 31);
    if (active) {
      floatx4 sacc[2][4];
#pragma unroll
      for (int i = 0; i < 2; i++)
#pragma unroll
        for (int j = 0; j < 4; j++) sacc[i][j] = (floatx4){0.f, 0.f, 0.f, 0.f};
#pragma unroll
      for (int c = 0; c < 4; c++) {
        short8 bk[4];
#pragma unroll
        for (int j = 0; j < 4; j++)
          bk[j] = *(const short8*)&Ks[(j * 16 + r) * 136 + c * 32 + q * 8];
#pragma unroll
        for (int i = 0; i < 2; i++)
#pragma unroll
          for (int j = 0; j < 4; j++)
            sacc[i][j] = __builtin_amdgcn_mfma_f32_16x16x32_bf16(qa[i][c], bk[j], sacc[i][j], 0, 0, 0);
      }
      const bool needmask = (kt * 64 + 63 > qt * 128 + w * 32);
#pragma unroll
      for (int i = 0; i < 2; i++) {
#pragma unroll
        for (int v = 0; v < 4; v++) {
          const int rowg = qt * 128 + w * 32 + i * 16 + q * 4 + v;
          float sv[4];
#pragma unroll
          for (int j = 0; j < 4; j++) sv[j] = sacc[i][j][v];
          if (needmask) {
#pragma unroll
            for (int j = 0; j < 4; j++)
              if (kt * 64 + j * 16 + r > rowg) sv[j] = -3.0e38f;
          }
          float rm = fmaxf(fmaxf(sv[0], sv[1]), fmaxf(sv[2], sv[3]));
#pragma unroll
          for (int off = 1; off < 16; off <<= 1)
            rm = fmaxf(rm, __shfl_xor(rm, off, 64));
          float mnew = fmaxf(m_i[i][v], rm);
          float alpha = exp2f(m_i[i][v] - mnew);
          m_i[i][v] = mnew;
          float ps[4], rsum = 0.f;
#pragma unroll
          for (int j = 0; j < 4; j++) { ps[j] = exp2f(sv[j] - mnew); rsum += ps[j]; }
#pragma unroll
          for (int off = 1; off < 16; off <<= 1)
            rsum += __shfl_xor(rsum, off, 64);
          l_i[i][v] = l_i[i][v] * alpha + rsum;
#pragma unroll
          for (int jd = 0; jd < 8; jd++) oacc[i][jd][v] *= alpha;
          const int prow = (w * 32 + i * 16 + q * 4 + v) * 72;
#pragma unroll
          for (int j = 0; j < 4; j++)
            Ps[prow + j * 16 + r] = f2bf_fast(ps[j]);
        }
      }
      // PV: wave reads only its own P rows (same-wave LDS, no barrier needed)
#pragma unroll
      for (int c = 0; c < 2; c++) {
        short8 pa[2];
#pragma unroll
        for (int i = 0; i < 2; i++)
          pa[i] = *(const short8*)&Ps[(w * 32 + i * 16 + r) * 72 + c * 32 + q * 8];
#pragma unroll
        for (int jd = 0; jd < 8; jd++) {
          short8 bv = *(const short8*)&Vts[(jd * 16 + r) * 72 + c * 32 + q * 8];
#pragma unroll
          for (int i = 0; i < 2; i++)
            oacc[i][jd] = __builtin_amdgcn_mfma_f32_16x16x32_bf16(pa[i], bv, oacc[i][jd], 0, 0, 0);
        }
      }
    }
    __syncthreads();
  }

  // epilogue: y[b, t, h*128 + d]
#pragma unroll
  for (int i = 0; i < 2; i++) {
#pragma unroll
    for (int v = 0; v < 4; v++) {
      const int rowg = qt * 128 + w * 32 + i * 16 + q * 4 + v;
      float inv = 1.0f / l_i[i][v];
      unsigned short* yr = y + ((size_t)(b * T_SEQ) + rowg) * DM + h * 128;
#pragma unroll
      for (int jd = 0; jd < 8; jd++)
        yr[jd * 16 + r] = f2bf(oacc[i][jd][v] * inv);
    }
  }
}

// ---------------------------------------------------------------------------
extern "C" void kernel_launch(void* const* d_in, const int* in_sizes, int n_in,
                              void* d_out, int out_size, void* d_ws, size_t ws_size,
                              hipStream_t stream) {
  const float* x      = (const float*)d_in[0];
  const float* Wdq_w  = (const float*)d_in[1];
  const float* Wdq_b  = (const float*)d_in[2];
  const float* qn_g   = (const float*)d_in[3];
  const float* qn_b   = (const float*)d_in[4];
  const float* Wuq_w  = (const float*)d_in[5];
  const float* Wuq_b  = (const float*)d_in[6];
  const float* Wdkv_w = (const float*)d_in[7];
  const float* Wdkv_b = (const float*)d_in[8];
  const float* kvn_g  = (const float*)d_in[9];
  const float* kvn_b  = (const float*)d_in[10];
  const float* Wukv_w = (const float*)d_in[11];
  const float* Wukv_b = (const float*)d_in[12];
  const float* Wo_w   = (const float*)d_in[13];
  const float* Wo_b   = (const float*)d_in[14];
  float* out = (float*)d_out;

  float* ws = (float*)d_ws;
  // float-unit offsets; regions reused across phases (lifetimes commented)
  unsigned short* x_bf    = (unsigned short*)(ws);             // 4096x2048 (dies after gemm4)
  unsigned short* y_bf    = (unsigned short*)(ws);             // alias: attn output
  unsigned short* Wdq_bf  = (unsigned short*)(ws + 4194304);   // 768x2048
  unsigned short* Wuq_bf  = (unsigned short*)(ws + 4980736);   // 2048x704
  unsigned short* Wdkv_bf = (unsigned short*)(ws + 5701632);   // 1152x2048
  unsigned short* Wukv_bf = (unsigned short*)(ws + 6881280);   // 3072x1024
  float* c_q    = ws + 8454144;                                // 4096x682 fp32
  unsigned short* c_q_bf = (unsigned short*)(ws + 11247616);   // 4096x704
  unsigned short* Q_all  = (unsigned short*)(ws + 8454144);    // alias after gemm3
  float* q_lin  = ws + 12689408;                               // 4096x2048 fp32
  unsigned short* K_all  = (unsigned short*)(ws + 12689408);   // alias after build_qfull
  unsigned short* Vt_all = (unsigned short*)(ws + 16883712);   // [b,h,d,t]
  float* c_kv   = ws + 21078016;                               // 4096x1088 fp32
  unsigned short* Wo_bf  = (unsigned short*)(ws + 21078016);   // alias after repack_k
  unsigned short* kvn_bf = (unsigned short*)(ws + 25534464);   // 4096x1024
  unsigned short* kv_bf  = (unsigned short*)(ws + 27631616);   // 4096x3072 bf16

  dim3 blk(256);

  cvt_bf16_pad<<<(4096L*2048 + 255) / 256, blk, 0, stream>>>(x, x_bf, 4096, 2048, 2048, 4096L*2048);
  cvt_bf16_pad<<<(768L*2048 + 255) / 256, blk, 0, stream>>>(Wdq_w, Wdq_bf, 682, 2048, 2048, 768L*2048);
  cvt_bf16_pad<<<(2048L*704 + 255) / 256, blk, 0, stream>>>(Wuq_w, Wuq_bf, 2048, 682, 704, 2048L*704);
  cvt_bf16_pad<<<(1152L*2048 + 255) / 256, blk, 0, stream>>>(Wdkv_w, Wdkv_bf, 1088, 2048, 2048, 1152L*2048);
  cvt_bf16_pad<<<(3072L*1024 + 255) / 256, blk, 0, stream>>>(Wukv_w, Wukv_bf, 3072, 1024, 1024, 3072L*1024);

  // c_q = x @ Wdq^T + b
  gemm_bf16<<<dim3(6, 32), blk, 0, stream>>>(x_bf, 2048, Wdq_bf, 2048, Wdq_b, c_q, DQ, DQ, 2048);
  // LN(c_q) -> bf16 (K-padded)
  ln_bf16_kernel<<<TOK, blk, 0, stream>>>(c_q, DQ, c_q_bf, DQP, qn_g, qn_b, DQ);
  // q_lin = c_q @ Wuq^T + b
  gemm_bf16<<<dim3(16, 32), blk, 0, stream>>>(c_q_bf, DQP, Wuq_bf, DQP, Wuq_b, q_lin, DM, DM, DQP);
  // c_kv = x @ Wdkv^T + b
  gemm_bf16<<<dim3(9, 32), blk, 0, stream>>>(x_bf, 2048, Wdkv_bf, 2048, Wdkv_b, c_kv, DCKV, DCKV, 2048);
  // kv_n = LN(c_kv[:, :1024]) -> bf16
  ln_bf16_kernel<<<TOK, blk, 0, stream>>>(c_kv, DCKV, kvn_bf, DKV, kvn_g, kvn_b, DKV);
  // kv = kv_n @ Wukv^T + b  (bf16 out)
  gemm_bf16_obf<<<dim3(24, 32), blk, 0, stream>>>(kvn_bf, DKV, Wukv_bf, DKV, Wukv_b, kv_bf, DUKV, DUKV, DKV);
  // Q_all bf16 (rotary-by-head, scale*log2e folded); q_lin dead after
  build_qfull_bf<<<(2 * NH * T_SEQ * 128) / 256, blk, 0, stream>>>(q_lin, Q_all);
  // K cache / V^T cache
  repack_k<<<(2 * NH * T_SEQ * 128) / 256, blk, 0, stream>>>(kv_bf, c_kv, K_all);
  repack_vt<<<(2 * NH * T_SEQ * 128) / 256, blk, 0, stream>>>(kv_bf, Vt_all);
  // Wo -> bf16 (into dead c_kv region)
  cvt_bf16_pad<<<(2048L*2048 + 255) / 256, blk, 0, stream>>>(Wo_w, Wo_bf, 2048, 2048, 2048, 2048L*2048);
  // attention -> y_bf
  attn_mfma<<<dim3(16, 16, 2), blk, 0, stream>>>(Q_all, K_all, Vt_all, y_bf);
  // out = y @ Wo^T + b
  gemm_bf16<<<dim3(16, 32), blk, 0, stream>>>(y_bf, 2048, Wo_bf, 2048, Wo_b, out, DM, DM, 2048);
}

// Round 6
// 592.456 us; speedup vs baseline: 10.4102x; 1.3394x over previous
//
#include <hip/hip_runtime.h>
#include <math.h>

#define TOK 4096
#define DM 2048
#define DQ 682
#define DQP 704
#define DCKV 1088
#define DKV 1024
#define DUKV 3072
#define NH 16
#define T_SEQ 2048

typedef __attribute__((ext_vector_type(8))) short short8;
typedef __attribute__((ext_vector_type(4))) float floatx4;

__device__ __forceinline__ unsigned short f2bf(float f) {
  union { float f; unsigned int u; } v; v.f = f;
  unsigned int u = v.u;
  u += 0x7fffu + ((u >> 16) & 1u);
  return (unsigned short)(u >> 16);
}
__device__ __forceinline__ unsigned short f2bf_fast(float f) {
  union { float f; unsigned int u; } v; v.f = f;
  return (unsigned short)((v.u + 0x8000u) >> 16);
}

typedef __attribute__((address_space(1))) const unsigned int as1_u32;
typedef __attribute__((address_space(3))) unsigned int as3_u32;
__device__ __forceinline__ void async16(const void* g, void* l) {
  __builtin_amdgcn_global_load_lds((as1_u32*)g, (as3_u32*)l, 16, 0, 0);
}

// ---------------------------------------------------------------------------
// bf16 MFMA GEMM (m97 structure), fp32 output. (verified R3/R4)
// ---------------------------------------------------------------------------
__global__ __launch_bounds__(256) void gemm_bf16(
    const unsigned short* __restrict__ A, int lda,
    const unsigned short* __restrict__ B, int ldb,
    const float* __restrict__ bias, float* __restrict__ C, int ldc,
    int Nvalid, int K)
{
  __shared__ __align__(16) unsigned short As[128 * 32];
  __shared__ __align__(16) unsigned short Bs[128 * 32];
  const int tid = threadIdx.x;
  const int w = tid >> 6;
  const int lane = tid & 63;
  const int q = lane >> 4;
  const int r = lane & 15;
  const int bm = blockIdx.y * 128;
  const int bn = blockIdx.x * 128;

  floatx4 acc[4][4];
#pragma unroll
  for (int i = 0; i < 4; i++)
#pragma unroll
    for (int j = 0; j < 4; j++) acc[i][j] = (floatx4){0.f, 0.f, 0.f, 0.f};

  const int srow = tid >> 2;
  const int scol = (tid & 3) * 8;
  const unsigned short* Ag0 = A + (size_t)(bm + srow) * lda + scol;
  const unsigned short* Ag1 = A + (size_t)(bm + 64 + srow) * lda + scol;
  const unsigned short* Bg0 = B + (size_t)(bn + srow) * ldb + scol;
  const unsigned short* Bg1 = B + (size_t)(bn + 64 + srow) * ldb + scol;
  unsigned short* AsL0 = &As[w * 512];
  unsigned short* AsL1 = &As[2048 + w * 512];
  unsigned short* BsL0 = &Bs[w * 512];
  unsigned short* BsL1 = &Bs[2048 + w * 512];

  const int mrow0 = (w >> 1) * 64;
  const int ncol0 = (w & 1) * 64;

  for (int k0 = 0; k0 < K; k0 += 32) {
    async16(Ag0 + k0, AsL0);
    async16(Ag1 + k0, AsL1);
    async16(Bg0 + k0, BsL0);
    async16(Bg1 + k0, BsL1);
    __syncthreads();
    short8 a[4], b[4];
#pragma unroll
    for (int i = 0; i < 4; i++)
      a[i] = *(const short8*)&As[(mrow0 + i * 16 + r) * 32 + q * 8];
#pragma unroll
    for (int j = 0; j < 4; j++)
      b[j] = *(const short8*)&Bs[(ncol0 + j * 16 + r) * 32 + q * 8];
#pragma unroll
    for (int i = 0; i < 4; i++)
#pragma unroll
      for (int j = 0; j < 4; j++)
        acc[i][j] = __builtin_amdgcn_mfma_f32_16x16x32_bf16(a[i], b[j], acc[i][j], 0, 0, 0);
    __syncthreads();
  }

#pragma unroll
  for (int j = 0; j < 4; j++) {
    int gc = bn + ncol0 + j * 16 + r;
    if (gc >= Nvalid) continue;
    float bv = bias[gc];
#pragma unroll
    for (int i = 0; i < 4; i++) {
#pragma unroll
      for (int v = 0; v < 4; v++) {
        int gr = bm + mrow0 + i * 16 + q * 4 + v;
        C[(size_t)gr * ldc + gc] = acc[i][j][v] + bv;
      }
    }
  }
}

// ---------------------------------------------------------------------------
// Same GEMM, bf16 output (for kv).
// ---------------------------------------------------------------------------
__global__ __launch_bounds__(256) void gemm_bf16_obf(
    const unsigned short* __restrict__ A, int lda,
    const unsigned short* __restrict__ B, int ldb,
    const float* __restrict__ bias, unsigned short* __restrict__ C, int ldc,
    int Nvalid, int K)
{
  __shared__ __align__(16) unsigned short As[128 * 32];
  __shared__ __align__(16) unsigned short Bs[128 * 32];
  const int tid = threadIdx.x;
  const int w = tid >> 6;
  const int lane = tid & 63;
  const int q = lane >> 4;
  const int r = lane & 15;
  const int bm = blockIdx.y * 128;
  const int bn = blockIdx.x * 128;

  floatx4 acc[4][4];
#pragma unroll
  for (int i = 0; i < 4; i++)
#pragma unroll
    for (int j = 0; j < 4; j++) acc[i][j] = (floatx4){0.f, 0.f, 0.f, 0.f};

  const int srow = tid >> 2;
  const int scol = (tid & 3) * 8;
  const unsigned short* Ag0 = A + (size_t)(bm + srow) * lda + scol;
  const unsigned short* Ag1 = A + (size_t)(bm + 64 + srow) * lda + scol;
  const unsigned short* Bg0 = B + (size_t)(bn + srow) * ldb + scol;
  const unsigned short* Bg1 = B + (size_t)(bn + 64 + srow) * ldb + scol;
  unsigned short* AsL0 = &As[w * 512];
  unsigned short* AsL1 = &As[2048 + w * 512];
  unsigned short* BsL0 = &Bs[w * 512];
  unsigned short* BsL1 = &Bs[2048 + w * 512];

  const int mrow0 = (w >> 1) * 64;
  const int ncol0 = (w & 1) * 64;

  for (int k0 = 0; k0 < K; k0 += 32) {
    async16(Ag0 + k0, AsL0);
    async16(Ag1 + k0, AsL1);
    async16(Bg0 + k0, BsL0);
    async16(Bg1 + k0, BsL1);
    __syncthreads();
    short8 a[4], b[4];
#pragma unroll
    for (int i = 0; i < 4; i++)
      a[i] = *(const short8*)&As[(mrow0 + i * 16 + r) * 32 + q * 8];
#pragma unroll
    for (int j = 0; j < 4; j++)
      b[j] = *(const short8*)&Bs[(ncol0 + j * 16 + r) * 32 + q * 8];
#pragma unroll
    for (int i = 0; i < 4; i++)
#pragma unroll
      for (int j = 0; j < 4; j++)
        acc[i][j] = __builtin_amdgcn_mfma_f32_16x16x32_bf16(a[i], b[j], acc[i][j], 0, 0, 0);
    __syncthreads();
  }

#pragma unroll
  for (int j = 0; j < 4; j++) {
    int gc = bn + ncol0 + j * 16 + r;
    if (gc >= Nvalid) continue;
    float bv = bias[gc];
#pragma unroll
    for (int i = 0; i < 4; i++) {
#pragma unroll
      for (int v = 0; v < 4; v++) {
        int gr = bm + mrow0 + i * 16 + q * 4 + v;
        C[(size_t)gr * ldc + gc] = f2bf(acc[i][j][v] + bv);
      }
    }
  }
}

// ---------------------------------------------------------------------------
__global__ __launch_bounds__(256) void cvt_bf16_pad(
    const float* __restrict__ in, unsigned short* __restrict__ out,
    int irows, int icols, int ocols, long total)
{
  long idx = (long)blockIdx.x * 256 + threadIdx.x;
  if (idx >= total) return;
  int rr = (int)(idx / ocols);
  int cc = (int)(idx - (long)rr * ocols);
  out[idx] = (rr < irows && cc < icols) ? f2bf(in[(size_t)rr * icols + cc]) : 0;
}

// ---------------------------------------------------------------------------
__device__ __forceinline__ float block_sum(float v, float* sbuf) {
#pragma unroll
  for (int off = 32; off > 0; off >>= 1) v += __shfl_down(v, off, 64);
  int wid = threadIdx.x >> 6;
  __syncthreads();
  if ((threadIdx.x & 63) == 0) sbuf[wid] = v;
  __syncthreads();
  return sbuf[0] + sbuf[1] + sbuf[2] + sbuf[3];
}

__global__ __launch_bounds__(256) void ln_bf16_kernel(
    const float* __restrict__ in, int istride,
    unsigned short* __restrict__ out, int ocols,
    const float* __restrict__ g, const float* __restrict__ bta, int D)
{
  __shared__ float sbuf[4];
  size_t row = blockIdx.x;
  const float* xr = in + row * istride;
  float s = 0.f;
  for (int i = threadIdx.x; i < D; i += 256) s += xr[i];
  float mu = block_sum(s, sbuf) / (float)D;
  float v = 0.f;
  for (int i = threadIdx.x; i < D; i += 256) { float d = xr[i] - mu; v += d * d; }
  float var = block_sum(v, sbuf) / (float)D;
  float rstd = rsqrtf(var + 1e-5f);
  unsigned short* orow = out + row * ocols;
  for (int i = threadIdx.x; i < ocols; i += 256)
    orow[i] = (i < D) ? f2bf((xr[i] - mu) * rstd * g[i] + bta[i]) : 0;
}

// ---------------------------------------------------------------------------
// Q_all[b,h,t,128] bf16, rotary angle = h * 10000^(-j/32) (reference quirk),
// softmax scale * log2(e) folded in.
// ---------------------------------------------------------------------------
__global__ __launch_bounds__(256) void build_qfull_bf(
    const float* __restrict__ q_lin, unsigned short* __restrict__ qf)
{
  const float QS = (float)(0.08838834764831845 * 1.4426950408889634);
  size_t idx = (size_t)blockIdx.x * 256 + threadIdx.x;
  int d = (int)(idx & 127);
  size_t rr = idx >> 7;
  int t = (int)(rr & 2047);
  int h = (int)((rr >> 11) & 15);
  int b = (int)(rr >> 15);
  const float* src = q_lin + ((size_t)(b * T_SEQ + t) * DM) + h * 128;
  float val;
  if (d < 64) {
    val = src[d];
  } else {
    int j = d & 31;
    float freq = exp2f(-(float)j * (13.287712379549449f / 32.0f));
    float ang = (float)h * freq;
    float c = cosf(ang), sn = sinf(ang);
    float x1 = src[64 + j], x2 = src[96 + j];
    val = (d < 96) ? (x1 * c + x2 * sn) : (x2 * c - x1 * sn);
  }
  qf[idx] = f2bf(val * QS);
}

// ---------------------------------------------------------------------------
// K_blk: per (bh, kt) a contiguous 8192-elem tile laid out [c=4][row64][32],
// matching the attention LDS image (k rotary is identity per reference).
// idx bits: dlow 5 | tt 6 | dhi 2 | kt 5 | bh 5
// ---------------------------------------------------------------------------
__global__ __launch_bounds__(256) void repack_k_blk(
    const unsigned short* __restrict__ kv_bf, const float* __restrict__ ckv,
    unsigned short* __restrict__ K)
{
  int idx = blockIdx.x * 256 + threadIdx.x;
  int dlow = idx & 31;
  int tt   = (idx >> 5) & 63;
  int dhi  = (idx >> 11) & 3;
  int kt   = (idx >> 13) & 31;
  int bh   = idx >> 18;
  int d = dhi * 32 + dlow;
  int t = kt * 64 + tt;
  int b = bh >> 4, h = bh & 15;
  unsigned short val;
  if (d < 64)
    val = kv_bf[((size_t)(b * T_SEQ + t)) * DUKV + h * 192 + d];
  else
    val = f2bf(ckv[((size_t)(b * T_SEQ + t)) * DCKV + 1024 + (d - 64)]);
  K[idx] = val;
}

// ---------------------------------------------------------------------------
// V_blk: per (bh, kt) contiguous 8192-elem tile [c2=2][d128][32] = V^T image.
// LDS tile transpose: coalesced reads AND writes.
// BUGFIX R5->R6: write loop is 4 iterations (8192 elems), not 8 (was writing
// 2x the tile: clobbered neighbor tiles + OOB LDS reads -> absmax 3.47).
// ---------------------------------------------------------------------------
__global__ __launch_bounds__(256) void repack_v_blk(
    const unsigned short* __restrict__ kv_bf, unsigned short* __restrict__ V)
{
  __shared__ unsigned short T[64 * 132];
  int kt = blockIdx.x, bh = blockIdx.y;
  int b = bh >> 4, h = bh & 15;
  int tid = threadIdx.x;
  // read 64 t-rows x 128 d, coalesced (4 contig shorts per thread)
#pragma unroll
  for (int p = 0; p < 8; p++) {
    int t = p * 8 + (tid >> 5);
    int dbase = (tid & 31) * 4;
    const unsigned short* src =
        kv_bf + ((size_t)(b * T_SEQ + kt * 64 + t)) * DUKV + h * 192 + 64 + dbase;
    unsigned short v0 = src[0], v1 = src[1], v2 = src[2], v3 = src[3];
    unsigned short* dst = &T[t * 132 + dbase];
    dst[0] = v0; dst[1] = v1; dst[2] = v2; dst[3] = v3;
  }
  __syncthreads();
  unsigned short* out = V + ((size_t)(bh * 32 + kt)) * 8192;
#pragma unroll
  for (int p = 0; p < 4; p++) {
    int o = p * 2048 + tid * 8;   // 8 consecutive out elems (t fastest)
    int c2 = o >> 12;
    int dd = (o >> 5) & 127;
    int tl = o & 31;
    short8 pack;
#pragma unroll
    for (int i = 0; i < 8; i++)
      pack[i] = (short)T[(c2 * 32 + tl + i) * 132 + dd];
    *(short8*)&out[o] = pack;
  }
}

// ---------------------------------------------------------------------------
// S^T-form MFMA flash attention.
// Block = (qt 64-row Q tile, h, b), 4 waves; wave w owns rows w*16..w*16+15.
// mfma(K_frag, Q_frag) -> S^T (col = qrow = lane&15): each lane holds all 16
// scores of ONE Q-row -> in-lane softmax + 2 shfl_xor. P via wave-private LDS
// roundtrip (R4-verified). PV: mfma(V^T_frag, P_frag) -> O^T; epilogue writes
// 4-contiguous bf16. K/V staged tile-linear via global_load_lds width=16.
// ---------------------------------------------------------------------------
__global__ __launch_bounds__(256) void attn_mfma2(
    const unsigned short* __restrict__ Qall,
    const unsigned short* __restrict__ Kblk,
    const unsigned short* __restrict__ Vblk,
    unsigned short* __restrict__ y)
{
  __shared__ __align__(16) unsigned short sm[8192 + 8192 + 4 * 16 * 72];
  unsigned short* Ks = sm;             // [4][64][32]
  unsigned short* Vs = sm + 8192;      // [2][128][32]
  unsigned short* Ps = sm + 16384;     // [wave][16][72]
  const int qt = 31 - (int)blockIdx.x;     // heavy-first
  const int h = blockIdx.y, b = blockIdx.z;
  const int tid = threadIdx.x;
  const int w = tid >> 6, lane = tid & 63, q = lane >> 4, r = lane & 15;
  const int bh = b * NH + h;

  // Q fragments (B-operand: lane r = qrow, 8 contig k at q*8)
  const unsigned short* Qrow =
      Qall + ((size_t)bh * T_SEQ + (size_t)qt * 64 + w * 16 + r) * 128 + q * 8;
  short8 qb[4];
#pragma unroll
  for (int c = 0; c < 4; c++) qb[c] = *(const short8*)(Qrow + c * 32);

  floatx4 oacc[8];
#pragma unroll
  for (int jd = 0; jd < 8; jd++) oacc[jd] = (floatx4){0.f, 0.f, 0.f, 0.f};
  float m_i = -3.0e38f, l_i = 0.f;

  const char* Kg0 = (const char*)(Kblk + ((size_t)(bh * 32)) * 8192);
  const char* Vg0 = (const char*)(Vblk + ((size_t)(bh * 32)) * 8192);
  char* KsB = (char*)Ks;
  char* VsB = (char*)Vs;
  unsigned short* Psw = Ps + w * (16 * 72);

  for (int kt = 0; kt <= qt; kt++) {
    const char* Kg = Kg0 + (size_t)kt * 16384;
    const char* Vg = Vg0 + (size_t)kt * 16384;
#pragma unroll
    for (int i = 0; i < 4; i++) {
      async16(Kg + i * 4096 + w * 1024 + lane * 16, KsB + i * 4096 + w * 1024);
      async16(Vg + i * 4096 + w * 1024 + lane * 16, VsB + i * 4096 + w * 1024);
    }
    __syncthreads();

    // S^T = K_tile * Q^T
    floatx4 sacc[4];
#pragma unroll
    for (int j = 0; j < 4; j++) sacc[j] = (floatx4){0.f, 0.f, 0.f, 0.f};
#pragma unroll
    for (int c = 0; c < 4; c++) {
      short8 ak[4];
#pragma unroll
      for (int j = 0; j < 4; j++)
        ak[j] = *(const short8*)&Ks[c * 2048 + (j * 16 + r) * 32 + q * 8];
#pragma unroll
      for (int j = 0; j < 4; j++)
        sacc[j] = __builtin_amdgcn_mfma_f32_16x16x32_bf16(ak[j], qb[c], sacc[j], 0, 0, 0);
    }

    // in-lane softmax for row (qt*64 + w*16 + r)
    float sv[16];
#pragma unroll
    for (int j = 0; j < 4; j++)
#pragma unroll
      for (int v = 0; v < 4; v++) sv[j * 4 + v] = sacc[j][v];
    if (kt == qt) {
      const int qrow = w * 16 + r;
#pragma unroll
      for (int j = 0; j < 4; j++)
#pragma unroll
        for (int v = 0; v < 4; v++)
          if (j * 16 + q * 4 + v > qrow) sv[j * 4 + v] = -3.0e38f;
    }
    float rm = sv[0];
#pragma unroll
    for (int t16 = 1; t16 < 16; t16++) rm = fmaxf(rm, sv[t16]);
    rm = fmaxf(rm, __shfl_xor(rm, 16, 64));
    rm = fmaxf(rm, __shfl_xor(rm, 32, 64));
    float mnew = fmaxf(m_i, rm);
    float alpha = exp2f(m_i - mnew);
    m_i = mnew;
    float p[16], rsum = 0.f;
#pragma unroll
    for (int t16 = 0; t16 < 16; t16++) { p[t16] = exp2f(sv[t16] - mnew); rsum += p[t16]; }
    rsum += __shfl_xor(rsum, 16, 64);
    rsum += __shfl_xor(rsum, 32, 64);
    l_i = l_i * alpha + rsum;
#pragma unroll
    for (int jd = 0; jd < 8; jd++) {
      oacc[jd][0] *= alpha; oacc[jd][1] *= alpha;
      oacc[jd][2] *= alpha; oacc[jd][3] *= alpha;
    }
    // P -> wave-private LDS (row r, cols j*16+q*4+v), then read as B-frags
#pragma unroll
    for (int j = 0; j < 4; j++)
#pragma unroll
      for (int v = 0; v < 4; v++)
        Psw[r * 72 + j * 16 + q * 4 + v] = f2bf_fast(p[j * 4 + v]);

    // O^T += V^T * P^T
#pragma unroll
    for (int c2 = 0; c2 < 2; c2++) {
      short8 pb = *(const short8*)&Psw[r * 72 + c2 * 32 + q * 8];
#pragma unroll
      for (int jd = 0; jd < 8; jd++) {
        short8 bv = *(const short8*)&Vs[c2 * 4096 + (jd * 16 + r) * 32 + q * 8];
        oacc[jd] = __builtin_amdgcn_mfma_f32_16x16x32_bf16(bv, pb, oacc[jd], 0, 0, 0);
      }
    }
    __syncthreads();
  }

  // epilogue: O^T lane holds rows d = jd*16+q*4+v, col qrow=r
  float inv = 1.0f / l_i;
  unsigned short* yr =
      y + ((size_t)(b * T_SEQ) + (size_t)qt * 64 + w * 16 + r) * DM + h * 128;
#pragma unroll
  for (int jd = 0; jd < 8; jd++) {
    unsigned short o0 = f2bf(oacc[jd][0] * inv);
    unsigned short o1 = f2bf(oacc[jd][1] * inv);
    unsigned short o2 = f2bf(oacc[jd][2] * inv);
    unsigned short o3 = f2bf(oacc[jd][3] * inv);
    unsigned int lo = (unsigned int)o0 | ((unsigned int)o1 << 16);
    unsigned int hi = (unsigned int)o2 | ((unsigned int)o3 << 16);
    unsigned int* dst = (unsigned int*)(yr + jd * 16 + q * 4);
    dst[0] = lo; dst[1] = hi;
  }
}

// ---------------------------------------------------------------------------
extern "C" void kernel_launch(void* const* d_in, const int* in_sizes, int n_in,
                              void* d_out, int out_size, void* d_ws, size_t ws_size,
                              hipStream_t stream) {
  const float* x      = (const float*)d_in[0];
  const float* Wdq_w  = (const float*)d_in[1];
  const float* Wdq_b  = (const float*)d_in[2];
  const float* qn_g   = (const float*)d_in[3];
  const float* qn_b   = (const float*)d_in[4];
  const float* Wuq_w  = (const float*)d_in[5];
  const float* Wuq_b  = (const float*)d_in[6];
  const float* Wdkv_w = (const float*)d_in[7];
  const float* Wdkv_b = (const float*)d_in[8];
  const float* kvn_g  = (const float*)d_in[9];
  const float* kvn_b  = (const float*)d_in[10];
  const float* Wukv_w = (const float*)d_in[11];
  const float* Wukv_b = (const float*)d_in[12];
  const float* Wo_w   = (const float*)d_in[13];
  const float* Wo_b   = (const float*)d_in[14];
  float* out = (float*)d_out;

  float* ws = (float*)d_ws;
  // region lifetimes commented; offsets in float units
  unsigned short* x_bf    = (unsigned short*)(ws);             // dies after gemm c_kv
  unsigned short* y_bf    = (unsigned short*)(ws);             // alias: attn output
  unsigned short* Wdq_bf  = (unsigned short*)(ws + 4194304);
  unsigned short* Wuq_bf  = (unsigned short*)(ws + 4980736);
  unsigned short* Wdkv_bf = (unsigned short*)(ws + 5701632);
  unsigned short* Wukv_bf = (unsigned short*)(ws + 6881280);   // ends 8454144
  float* c_q    = ws + 8454144;                                // dies after LN
  unsigned short* Q_all  = (unsigned short*)(ws + 8454144);    // alias after gemm q_lin
  unsigned short* c_q_bf = (unsigned short*)(ws + 11247616);   // dies after gemm q_lin
  float* q_lin  = ws + 12689408;                               // dies after build_qfull
  unsigned short* K_blk  = (unsigned short*)(ws + 12689408);   // alias after build_qfull
  unsigned short* V_blk  = (unsigned short*)(ws + 16883712);
  float* c_kv   = ws + 21078016;                               // dies after repack_k
  unsigned short* Wo_bf  = (unsigned short*)(ws + 21078016);   // alias after repack_k
  unsigned short* kvn_bf = (unsigned short*)(ws + 25534464);
  unsigned short* kv_bf  = (unsigned short*)(ws + 27631616);

  dim3 blk(256);

  cvt_bf16_pad<<<(4096L*2048 + 255) / 256, blk, 0, stream>>>(x, x_bf, 4096, 2048, 2048, 4096L*2048);
  cvt_bf16_pad<<<(768L*2048 + 255) / 256, blk, 0, stream>>>(Wdq_w, Wdq_bf, 682, 2048, 2048, 768L*2048);
  cvt_bf16_pad<<<(2048L*704 + 255) / 256, blk, 0, stream>>>(Wuq_w, Wuq_bf, 2048, 682, 704, 2048L*704);
  cvt_bf16_pad<<<(1152L*2048 + 255) / 256, blk, 0, stream>>>(Wdkv_w, Wdkv_bf, 1088, 2048, 2048, 1152L*2048);
  cvt_bf16_pad<<<(3072L*1024 + 255) / 256, blk, 0, stream>>>(Wukv_w, Wukv_bf, 3072, 1024, 1024, 3072L*1024);

  gemm_bf16<<<dim3(6, 32), blk, 0, stream>>>(x_bf, 2048, Wdq_bf, 2048, Wdq_b, c_q, DQ, DQ, 2048);
  ln_bf16_kernel<<<TOK, blk, 0, stream>>>(c_q, DQ, c_q_bf, DQP, qn_g, qn_b, DQ);
  gemm_bf16<<<dim3(16, 32), blk, 0, stream>>>(c_q_bf, DQP, Wuq_bf, DQP, Wuq_b, q_lin, DM, DM, DQP);
  gemm_bf16<<<dim3(9, 32), blk, 0, stream>>>(x_bf, 2048, Wdkv_bf, 2048, Wdkv_b, c_kv, DCKV, DCKV, 2048);
  ln_bf16_kernel<<<TOK, blk, 0, stream>>>(c_kv, DCKV, kvn_bf, DKV, kvn_g, kvn_b, DKV);
  gemm_bf16_obf<<<dim3(24, 32), blk, 0, stream>>>(kvn_bf, DKV, Wukv_bf, DKV, Wukv_b, kv_bf, DUKV, DUKV, DKV);

  build_qfull_bf<<<(2 * NH * T_SEQ * 128) / 256, blk, 0, stream>>>(q_lin, Q_all);
  repack_k_blk<<<(2 * NH * T_SEQ * 128) / 256, blk, 0, stream>>>(kv_bf, c_kv, K_blk);
  repack_v_blk<<<dim3(32, 32), blk, 0, stream>>>(kv_bf, V_blk);
  cvt_bf16_pad<<<(2048L*2048 + 255) / 256, blk, 0, stream>>>(Wo_w, Wo_bf, 2048, 2048, 2048, 2048L*2048);

  attn_mfma2<<<dim3(32, 16, 2), blk, 0, stream>>>(Q_all, K_blk, V_blk, y_bf);

  gemm_bf16<<<dim3(16, 32), blk, 0, stream>>>(y_bf, 2048, Wo_bf, 2048, Wo_b, out, DM, DM, 2048);
}

// Round 7
// 564.015 us; speedup vs baseline: 10.9351x; 1.0504x over previous
//
#include <hip/hip_runtime.h>
#include <math.h>

#define TOK 4096
#define DM 2048
#define DQ 682
#define DQP 704
#define DCKV 1088
#define DKV 1024
#define DUKV 3072
#define NH 16
#define T_SEQ 2048

typedef __attribute__((ext_vector_type(8))) short short8;
typedef __attribute__((ext_vector_type(4))) float floatx4;

__device__ __forceinline__ unsigned short f2bf(float f) {
  union { float f; unsigned int u; } v; v.f = f;
  unsigned int u = v.u;
  u += 0x7fffu + ((u >> 16) & 1u);
  return (unsigned short)(u >> 16);
}
__device__ __forceinline__ unsigned short f2bf_fast(float f) {
  union { float f; unsigned int u; } v; v.f = f;
  return (unsigned short)((v.u + 0x8000u) >> 16);
}

typedef __attribute__((address_space(1))) const unsigned int as1_u32;
typedef __attribute__((address_space(3))) unsigned int as3_u32;
__device__ __forceinline__ void async16(const void* g, void* l) {
  __builtin_amdgcn_global_load_lds((as1_u32*)g, (as3_u32*)l, 16, 0, 0);
}

// ---------------------------------------------------------------------------
// bf16 MFMA GEMM (m97 structure), fp32 output. (verified R3/R4/R6)
// ---------------------------------------------------------------------------
__global__ __launch_bounds__(256) void gemm_bf16(
    const unsigned short* __restrict__ A, int lda,
    const unsigned short* __restrict__ B, int ldb,
    const float* __restrict__ bias, float* __restrict__ C, int ldc,
    int Nvalid, int K)
{
  __shared__ __align__(16) unsigned short As[128 * 32];
  __shared__ __align__(16) unsigned short Bs[128 * 32];
  const int tid = threadIdx.x;
  const int w = tid >> 6;
  const int lane = tid & 63;
  const int q = lane >> 4;
  const int r = lane & 15;
  const int bm = blockIdx.y * 128;
  const int bn = blockIdx.x * 128;

  floatx4 acc[4][4];
#pragma unroll
  for (int i = 0; i < 4; i++)
#pragma unroll
    for (int j = 0; j < 4; j++) acc[i][j] = (floatx4){0.f, 0.f, 0.f, 0.f};

  const int srow = tid >> 2;
  const int scol = (tid & 3) * 8;
  const unsigned short* Ag0 = A + (size_t)(bm + srow) * lda + scol;
  const unsigned short* Ag1 = A + (size_t)(bm + 64 + srow) * lda + scol;
  const unsigned short* Bg0 = B + (size_t)(bn + srow) * ldb + scol;
  const unsigned short* Bg1 = B + (size_t)(bn + 64 + srow) * ldb + scol;
  unsigned short* AsL0 = &As[w * 512];
  unsigned short* AsL1 = &As[2048 + w * 512];
  unsigned short* BsL0 = &Bs[w * 512];
  unsigned short* BsL1 = &Bs[2048 + w * 512];

  const int mrow0 = (w >> 1) * 64;
  const int ncol0 = (w & 1) * 64;

  for (int k0 = 0; k0 < K; k0 += 32) {
    async16(Ag0 + k0, AsL0);
    async16(Ag1 + k0, AsL1);
    async16(Bg0 + k0, BsL0);
    async16(Bg1 + k0, BsL1);
    __syncthreads();
    short8 a[4], b[4];
#pragma unroll
    for (int i = 0; i < 4; i++)
      a[i] = *(const short8*)&As[(mrow0 + i * 16 + r) * 32 + q * 8];
#pragma unroll
    for (int j = 0; j < 4; j++)
      b[j] = *(const short8*)&Bs[(ncol0 + j * 16 + r) * 32 + q * 8];
#pragma unroll
    for (int i = 0; i < 4; i++)
#pragma unroll
      for (int j = 0; j < 4; j++)
        acc[i][j] = __builtin_amdgcn_mfma_f32_16x16x32_bf16(a[i], b[j], acc[i][j], 0, 0, 0);
    __syncthreads();
  }

#pragma unroll
  for (int j = 0; j < 4; j++) {
    int gc = bn + ncol0 + j * 16 + r;
    if (gc >= Nvalid) continue;
    float bv = bias[gc];
#pragma unroll
    for (int i = 0; i < 4; i++) {
#pragma unroll
      for (int v = 0; v < 4; v++) {
        int gr = bm + mrow0 + i * 16 + q * 4 + v;
        C[(size_t)gr * ldc + gc] = acc[i][j][v] + bv;
      }
    }
  }
}

// ---------------------------------------------------------------------------
// Same GEMM, bf16 output (for kv).
// ---------------------------------------------------------------------------
__global__ __launch_bounds__(256) void gemm_bf16_obf(
    const unsigned short* __restrict__ A, int lda,
    const unsigned short* __restrict__ B, int ldb,
    const float* __restrict__ bias, unsigned short* __restrict__ C, int ldc,
    int Nvalid, int K)
{
  __shared__ __align__(16) unsigned short As[128 * 32];
  __shared__ __align__(16) unsigned short Bs[128 * 32];
  const int tid = threadIdx.x;
  const int w = tid >> 6;
  const int lane = tid & 63;
  const int q = lane >> 4;
  const int r = lane & 15;
  const int bm = blockIdx.y * 128;
  const int bn = blockIdx.x * 128;

  floatx4 acc[4][4];
#pragma unroll
  for (int i = 0; i < 4; i++)
#pragma unroll
    for (int j = 0; j < 4; j++) acc[i][j] = (floatx4){0.f, 0.f, 0.f, 0.f};

  const int srow = tid >> 2;
  const int scol = (tid & 3) * 8;
  const unsigned short* Ag0 = A + (size_t)(bm + srow) * lda + scol;
  const unsigned short* Ag1 = A + (size_t)(bm + 64 + srow) * lda + scol;
  const unsigned short* Bg0 = B + (size_t)(bn + srow) * ldb + scol;
  const unsigned short* Bg1 = B + (size_t)(bn + 64 + srow) * ldb + scol;
  unsigned short* AsL0 = &As[w * 512];
  unsigned short* AsL1 = &As[2048 + w * 512];
  unsigned short* BsL0 = &Bs[w * 512];
  unsigned short* BsL1 = &Bs[2048 + w * 512];

  const int mrow0 = (w >> 1) * 64;
  const int ncol0 = (w & 1) * 64;

  for (int k0 = 0; k0 < K; k0 += 32) {
    async16(Ag0 + k0, AsL0);
    async16(Ag1 + k0, AsL1);
    async16(Bg0 + k0, BsL0);
    async16(Bg1 + k0, BsL1);
    __syncthreads();
    short8 a[4], b[4];
#pragma unroll
    for (int i = 0; i < 4; i++)
      a[i] = *(const short8*)&As[(mrow0 + i * 16 + r) * 32 + q * 8];
#pragma unroll
    for (int j = 0; j < 4; j++)
      b[j] = *(const short8*)&Bs[(ncol0 + j * 16 + r) * 32 + q * 8];
#pragma unroll
    for (int i = 0; i < 4; i++)
#pragma unroll
      for (int j = 0; j < 4; j++)
        acc[i][j] = __builtin_amdgcn_mfma_f32_16x16x32_bf16(a[i], b[j], acc[i][j], 0, 0, 0);
    __syncthreads();
  }

#pragma unroll
  for (int j = 0; j < 4; j++) {
    int gc = bn + ncol0 + j * 16 + r;
    if (gc >= Nvalid) continue;
    float bv = bias[gc];
#pragma unroll
    for (int i = 0; i < 4; i++) {
#pragma unroll
      for (int v = 0; v < 4; v++) {
        int gr = bm + mrow0 + i * 16 + q * 4 + v;
        C[(size_t)gr * ldc + gc] = f2bf(acc[i][j][v] + bv);
      }
    }
  }
}

// ---------------------------------------------------------------------------
__global__ __launch_bounds__(256) void cvt_bf16_pad(
    const float* __restrict__ in, unsigned short* __restrict__ out,
    int irows, int icols, int ocols, long total)
{
  long idx = (long)blockIdx.x * 256 + threadIdx.x;
  if (idx >= total) return;
  int rr = (int)(idx / ocols);
  int cc = (int)(idx - (long)rr * ocols);
  out[idx] = (rr < irows && cc < icols) ? f2bf(in[(size_t)rr * icols + cc]) : 0;
}

// ---------------------------------------------------------------------------
__device__ __forceinline__ float block_sum(float v, float* sbuf) {
#pragma unroll
  for (int off = 32; off > 0; off >>= 1) v += __shfl_down(v, off, 64);
  int wid = threadIdx.x >> 6;
  __syncthreads();
  if ((threadIdx.x & 63) == 0) sbuf[wid] = v;
  __syncthreads();
  return sbuf[0] + sbuf[1] + sbuf[2] + sbuf[3];
}

__global__ __launch_bounds__(256) void ln_bf16_kernel(
    const float* __restrict__ in, int istride,
    unsigned short* __restrict__ out, int ocols,
    const float* __restrict__ g, const float* __restrict__ bta, int D)
{
  __shared__ float sbuf[4];
  size_t row = blockIdx.x;
  const float* xr = in + row * istride;
  float s = 0.f;
  for (int i = threadIdx.x; i < D; i += 256) s += xr[i];
  float mu = block_sum(s, sbuf) / (float)D;
  float v = 0.f;
  for (int i = threadIdx.x; i < D; i += 256) { float d = xr[i] - mu; v += d * d; }
  float var = block_sum(v, sbuf) / (float)D;
  float rstd = rsqrtf(var + 1e-5f);
  unsigned short* orow = out + row * ocols;
  for (int i = threadIdx.x; i < ocols; i += 256)
    orow[i] = (i < D) ? f2bf((xr[i] - mu) * rstd * g[i] + bta[i]) : 0;
}

// ---------------------------------------------------------------------------
// Q_all[b,h,t,128] bf16, rotary angle = h * 10000^(-j/32) (reference quirk),
// softmax scale * log2(e) folded in.
// ---------------------------------------------------------------------------
__global__ __launch_bounds__(256) void build_qfull_bf(
    const float* __restrict__ q_lin, unsigned short* __restrict__ qf)
{
  const float QS = (float)(0.08838834764831845 * 1.4426950408889634);
  size_t idx = (size_t)blockIdx.x * 256 + threadIdx.x;
  int d = (int)(idx & 127);
  size_t rr = idx >> 7;
  int t = (int)(rr & 2047);
  int h = (int)((rr >> 11) & 15);
  int b = (int)(rr >> 15);
  const float* src = q_lin + ((size_t)(b * T_SEQ + t) * DM) + h * 128;
  float val;
  if (d < 64) {
    val = src[d];
  } else {
    int j = d & 31;
    float freq = exp2f(-(float)j * (13.287712379549449f / 32.0f));
    float ang = (float)h * freq;
    float c = cosf(ang), sn = sinf(ang);
    float x1 = src[64 + j], x2 = src[96 + j];
    val = (d < 96) ? (x1 * c + x2 * sn) : (x2 * c - x1 * sn);
  }
  qf[idx] = f2bf(val * QS);
}

// ---------------------------------------------------------------------------
// K_blk: per (bh, kt) contiguous 8192-elem tile [c=4][row64][32] (attention
// LDS image; k rotary identity per reference quirk).
// ---------------------------------------------------------------------------
__global__ __launch_bounds__(256) void repack_k_blk(
    const unsigned short* __restrict__ kv_bf, const float* __restrict__ ckv,
    unsigned short* __restrict__ K)
{
  int idx = blockIdx.x * 256 + threadIdx.x;
  int dlow = idx & 31;
  int tt   = (idx >> 5) & 63;
  int dhi  = (idx >> 11) & 3;
  int kt   = (idx >> 13) & 31;
  int bh   = idx >> 18;
  int d = dhi * 32 + dlow;
  int t = kt * 64 + tt;
  int b = bh >> 4, h = bh & 15;
  unsigned short val;
  if (d < 64)
    val = kv_bf[((size_t)(b * T_SEQ + t)) * DUKV + h * 192 + d];
  else
    val = f2bf(ckv[((size_t)(b * T_SEQ + t)) * DCKV + 1024 + (d - 64)]);
  K[idx] = val;
}

// ---------------------------------------------------------------------------
// V_blk: per (bh, kt) contiguous 8192-elem tile [c2=2][d128][32] = V^T image.
// (R6-fixed: write loop covers exactly 8192 elems.)
// ---------------------------------------------------------------------------
__global__ __launch_bounds__(256) void repack_v_blk(
    const unsigned short* __restrict__ kv_bf, unsigned short* __restrict__ V)
{
  __shared__ unsigned short T[64 * 132];
  int kt = blockIdx.x, bh = blockIdx.y;
  int b = bh >> 4, h = bh & 15;
  int tid = threadIdx.x;
#pragma unroll
  for (int p = 0; p < 8; p++) {
    int t = p * 8 + (tid >> 5);
    int dbase = (tid & 31) * 4;
    const unsigned short* src =
        kv_bf + ((size_t)(b * T_SEQ + kt * 64 + t)) * DUKV + h * 192 + 64 + dbase;
    unsigned short v0 = src[0], v1 = src[1], v2 = src[2], v3 = src[3];
    unsigned short* dst = &T[t * 132 + dbase];
    dst[0] = v0; dst[1] = v1; dst[2] = v2; dst[3] = v3;
  }
  __syncthreads();
  unsigned short* out = V + ((size_t)(bh * 32 + kt)) * 8192;
#pragma unroll
  for (int p = 0; p < 4; p++) {
    int o = p * 2048 + tid * 8;
    int c2 = o >> 12;
    int dd = (o >> 5) & 127;
    int tl = o & 31;
    short8 pack;
#pragma unroll
    for (int i = 0; i < 8; i++)
      pack[i] = (short)T[(c2 * 32 + tl + i) * 132 + dd];
    *(short8*)&out[o] = pack;
  }
}

// ---------------------------------------------------------------------------
// attn v3: S^T-form MFMA flash attention, 128-row Q tiles, K/V double-buffered
// prefetch (loads for kt+1 issued right after the iter-top barrier; the
// barrier's vmcnt(0) drain lands a full compute-phase later). 4 waves; wave w
// owns 32 Q rows as 2 groups of 16 (Sᵀ math identical to R6 per group; ak
// K-frags shared across groups). Grid x: qt = x<8 ? 15-x : x-8 so CU slot i
// pairs with i+256 at constant total work (balanced, 2 blocks/CU, no tail).
// LDS 74,752 B -> 2 blocks/CU.
// ---------------------------------------------------------------------------
__global__ __launch_bounds__(256, 2) void attn_mfma3(
    const unsigned short* __restrict__ Qall,
    const unsigned short* __restrict__ Kblk,
    const unsigned short* __restrict__ Vblk,
    unsigned short* __restrict__ y)
{
  __shared__ __align__(16) unsigned short sm[37376];
  // shorts: K buf0 @0, buf1 @8192; V buf0 @16384, buf1 @24576; Ps @32768+w*1152
  const int x = (int)blockIdx.x;
  const int qt = (x < 8) ? (15 - x) : (x - 8);
  const int h = blockIdx.y, b = blockIdx.z;
  const int tid = threadIdx.x;
  const int w = tid >> 6, lane = tid & 63, q = lane >> 4, r = lane & 15;
  const int bh = b * NH + h;

  // Q fragments for 2 groups (B-operand: lane r = qrow, 8 contig k at q*8)
  short8 qb[2][4];
#pragma unroll
  for (int g = 0; g < 2; g++) {
    const unsigned short* Qrow =
        Qall + ((size_t)bh * T_SEQ + (size_t)qt * 128 + w * 32 + g * 16 + r) * 128 + q * 8;
#pragma unroll
    for (int c = 0; c < 4; c++) qb[g][c] = *(const short8*)(Qrow + c * 32);
  }

  floatx4 oacc[2][8];
#pragma unroll
  for (int g = 0; g < 2; g++)
#pragma unroll
    for (int jd = 0; jd < 8; jd++) oacc[g][jd] = (floatx4){0.f, 0.f, 0.f, 0.f};
  float m_i[2] = {-3.0e38f, -3.0e38f}, l_i[2] = {0.f, 0.f};

  const char* Kg0 = (const char*)(Kblk + ((size_t)(bh * 32)) * 8192);
  const char* Vg0 = (const char*)(Vblk + ((size_t)(bh * 32)) * 8192);
  char* smB = (char*)sm;
  unsigned short* Psw = sm + 32768 + w * 1152;
  const int ktmax = 2 * qt + 1;

  // prologue: stage kt=0 into buffer 0
#pragma unroll
  for (int i = 0; i < 4; i++) {
    async16(Kg0 + i * 4096 + w * 1024 + lane * 16, smB + i * 4096 + w * 1024);
    async16(Vg0 + i * 4096 + w * 1024 + lane * 16, smB + 32768 + i * 4096 + w * 1024);
  }

  for (int kt = 0; kt <= ktmax; kt++) {
    const int cur = kt & 1;
    __syncthreads();  // drains loads for kt; prior iter's reads of buf cur done
    if (kt < ktmax) {
      const int nxt = cur ^ 1;
      const char* Kg = Kg0 + (size_t)(kt + 1) * 16384;
      const char* Vg = Vg0 + (size_t)(kt + 1) * 16384;
#pragma unroll
      for (int i = 0; i < 4; i++) {
        async16(Kg + i * 4096 + w * 1024 + lane * 16,
                smB + nxt * 16384 + i * 4096 + w * 1024);
        async16(Vg + i * 4096 + w * 1024 + lane * 16,
                smB + 32768 + nxt * 16384 + i * 4096 + w * 1024);
      }
    }

    const bool activeW = (kt * 64 <= qt * 128 + w * 32 + 31);
    if (activeW) {
      const unsigned short* KsC = sm + cur * 8192;
      const unsigned short* VsC = sm + 16384 + cur * 8192;

      // S^T = K_tile * Q^T for both groups (ak frags shared)
      floatx4 sacc[2][4];
#pragma unroll
      for (int g = 0; g < 2; g++)
#pragma unroll
        for (int j = 0; j < 4; j++) sacc[g][j] = (floatx4){0.f, 0.f, 0.f, 0.f};
#pragma unroll
      for (int c = 0; c < 4; c++) {
        short8 ak[4];
#pragma unroll
        for (int j = 0; j < 4; j++)
          ak[j] = *(const short8*)&KsC[c * 2048 + (j * 16 + r) * 32 + q * 8];
#pragma unroll
        for (int g = 0; g < 2; g++)
#pragma unroll
          for (int j = 0; j < 4; j++)
            sacc[g][j] = __builtin_amdgcn_mfma_f32_16x16x32_bf16(ak[j], qb[g][c], sacc[g][j], 0, 0, 0);
      }

#pragma unroll
      for (int g = 0; g < 2; g++) {
        // in-lane softmax for row (qt*128 + w*32 + g*16 + r)
        float sv[16];
#pragma unroll
        for (int j = 0; j < 4; j++)
#pragma unroll
          for (int v = 0; v < 4; v++) sv[j * 4 + v] = sacc[g][j][v];
        const int rel = qt * 128 + w * 32 + g * 16 + r - kt * 64;
        if (rel < 63) {
#pragma unroll
          for (int j = 0; j < 4; j++)
#pragma unroll
            for (int v = 0; v < 4; v++)
              if (j * 16 + q * 4 + v > rel) sv[j * 4 + v] = -3.0e38f;
        }
        float rm = sv[0];
#pragma unroll
        for (int t16 = 1; t16 < 16; t16++) rm = fmaxf(rm, sv[t16]);
        rm = fmaxf(rm, __shfl_xor(rm, 16, 64));
        rm = fmaxf(rm, __shfl_xor(rm, 32, 64));
        float mnew = fmaxf(m_i[g], rm);
        float alpha = exp2f(m_i[g] - mnew);
        m_i[g] = mnew;
        float p[16], rsum = 0.f;
#pragma unroll
        for (int t16 = 0; t16 < 16; t16++) { p[t16] = exp2f(sv[t16] - mnew); rsum += p[t16]; }
        rsum += __shfl_xor(rsum, 16, 64);
        rsum += __shfl_xor(rsum, 32, 64);
        l_i[g] = l_i[g] * alpha + rsum;
#pragma unroll
        for (int jd = 0; jd < 8; jd++) {
          oacc[g][jd][0] *= alpha; oacc[g][jd][1] *= alpha;
          oacc[g][jd][2] *= alpha; oacc[g][jd][3] *= alpha;
        }
        // P -> wave-private LDS roundtrip (R6-verified), then PV
#pragma unroll
        for (int j = 0; j < 4; j++)
#pragma unroll
          for (int v = 0; v < 4; v++)
            Psw[r * 72 + j * 16 + q * 4 + v] = f2bf_fast(p[j * 4 + v]);
#pragma unroll
        for (int c2 = 0; c2 < 2; c2++) {
          short8 pb = *(const short8*)&Psw[r * 72 + c2 * 32 + q * 8];
#pragma unroll
          for (int jd = 0; jd < 8; jd++) {
            short8 bv = *(const short8*)&VsC[c2 * 4096 + (jd * 16 + r) * 32 + q * 8];
            oacc[g][jd] = __builtin_amdgcn_mfma_f32_16x16x32_bf16(bv, pb, oacc[g][jd], 0, 0, 0);
          }
        }
      }
    }
  }

  // epilogue: O^T lane holds rows d = jd*16+q*4+v, col qrow=r (per group)
#pragma unroll
  for (int g = 0; g < 2; g++) {
    float inv = 1.0f / l_i[g];
    unsigned short* yr =
        y + ((size_t)(b * T_SEQ) + (size_t)qt * 128 + w * 32 + g * 16 + r) * DM + h * 128;
#pragma unroll
    for (int jd = 0; jd < 8; jd++) {
      unsigned short o0 = f2bf(oacc[g][jd][0] * inv);
      unsigned short o1 = f2bf(oacc[g][jd][1] * inv);
      unsigned short o2 = f2bf(oacc[g][jd][2] * inv);
      unsigned short o3 = f2bf(oacc[g][jd][3] * inv);
      unsigned int lo = (unsigned int)o0 | ((unsigned int)o1 << 16);
      unsigned int hi = (unsigned int)o2 | ((unsigned int)o3 << 16);
      unsigned int* dst = (unsigned int*)(yr + jd * 16 + q * 4);
      dst[0] = lo; dst[1] = hi;
    }
  }
}

// ---------------------------------------------------------------------------
extern "C" void kernel_launch(void* const* d_in, const int* in_sizes, int n_in,
                              void* d_out, int out_size, void* d_ws, size_t ws_size,
                              hipStream_t stream) {
  const float* x      = (const float*)d_in[0];
  const float* Wdq_w  = (const float*)d_in[1];
  const float* Wdq_b  = (const float*)d_in[2];
  const float* qn_g   = (const float*)d_in[3];
  const float* qn_b   = (const float*)d_in[4];
  const float* Wuq_w  = (const float*)d_in[5];
  const float* Wuq_b  = (const float*)d_in[6];
  const float* Wdkv_w = (const float*)d_in[7];
  const float* Wdkv_b = (const float*)d_in[8];
  const float* kvn_g  = (const float*)d_in[9];
  const float* kvn_b  = (const float*)d_in[10];
  const float* Wukv_w = (const float*)d_in[11];
  const float* Wukv_b = (const float*)d_in[12];
  const float* Wo_w   = (const float*)d_in[13];
  const float* Wo_b   = (const float*)d_in[14];
  float* out = (float*)d_out;

  float* ws = (float*)d_ws;
  unsigned short* x_bf    = (unsigned short*)(ws);             // dies after gemm c_kv
  unsigned short* y_bf    = (unsigned short*)(ws);             // alias: attn output
  unsigned short* Wdq_bf  = (unsigned short*)(ws + 4194304);
  unsigned short* Wuq_bf  = (unsigned short*)(ws + 4980736);
  unsigned short* Wdkv_bf = (unsigned short*)(ws + 5701632);
  unsigned short* Wukv_bf = (unsigned short*)(ws + 6881280);   // ends 8454144
  float* c_q    = ws + 8454144;                                // dies after LN
  unsigned short* Q_all  = (unsigned short*)(ws + 8454144);    // alias after gemm q_lin
  unsigned short* c_q_bf = (unsigned short*)(ws + 11247616);   // dies after gemm q_lin
  float* q_lin  = ws + 12689408;                               // dies after build_qfull
  unsigned short* K_blk  = (unsigned short*)(ws + 12689408);   // alias after build_qfull
  unsigned short* V_blk  = (unsigned short*)(ws + 16883712);
  float* c_kv   = ws + 21078016;                               // dies after repack_k
  unsigned short* Wo_bf  = (unsigned short*)(ws + 21078016);   // alias after repack_k
  unsigned short* kvn_bf = (unsigned short*)(ws + 25534464);
  unsigned short* kv_bf  = (unsigned short*)(ws + 27631616);

  dim3 blk(256);

  cvt_bf16_pad<<<(4096L*2048 + 255) / 256, blk, 0, stream>>>(x, x_bf, 4096, 2048, 2048, 4096L*2048);
  cvt_bf16_pad<<<(768L*2048 + 255) / 256, blk, 0, stream>>>(Wdq_w, Wdq_bf, 682, 2048, 2048, 768L*2048);
  cvt_bf16_pad<<<(2048L*704 + 255) / 256, blk, 0, stream>>>(Wuq_w, Wuq_bf, 2048, 682, 704, 2048L*704);
  cvt_bf16_pad<<<(1152L*2048 + 255) / 256, blk, 0, stream>>>(Wdkv_w, Wdkv_bf, 1088, 2048, 2048, 1152L*2048);
  cvt_bf16_pad<<<(3072L*1024 + 255) / 256, blk, 0, stream>>>(Wukv_w, Wukv_bf, 3072, 1024, 1024, 3072L*1024);

  gemm_bf16<<<dim3(6, 32), blk, 0, stream>>>(x_bf, 2048, Wdq_bf, 2048, Wdq_b, c_q, DQ, DQ, 2048);
  ln_bf16_kernel<<<TOK, blk, 0, stream>>>(c_q, DQ, c_q_bf, DQP, qn_g, qn_b, DQ);
  gemm_bf16<<<dim3(16, 32), blk, 0, stream>>>(c_q_bf, DQP, Wuq_bf, DQP, Wuq_b, q_lin, DM, DM, DQP);
  gemm_bf16<<<dim3(9, 32), blk, 0, stream>>>(x_bf, 2048, Wdkv_bf, 2048, Wdkv_b, c_kv, DCKV, DCKV, 2048);
  ln_bf16_kernel<<<TOK, blk, 0, stream>>>(c_kv, DCKV, kvn_bf, DKV, kvn_g, kvn_b, DKV);
  gemm_bf16_obf<<<dim3(24, 32), blk, 0, stream>>>(kvn_bf, DKV, Wukv_bf, DKV, Wukv_b, kv_bf, DUKV, DUKV, DKV);

  build_qfull_bf<<<(2 * NH * T_SEQ * 128) / 256, blk, 0, stream>>>(q_lin, Q_all);
  repack_k_blk<<<(2 * NH * T_SEQ * 128) / 256, blk, 0, stream>>>(kv_bf, c_kv, K_blk);
  repack_v_blk<<<dim3(32, 32), blk, 0, stream>>>(kv_bf, V_blk);
  cvt_bf16_pad<<<(2048L*2048 + 255) / 256, blk, 0, stream>>>(Wo_w, Wo_bf, 2048, 2048, 2048, 2048L*2048);

  attn_mfma3<<<dim3(16, 16, 2), blk, 0, stream>>>(Q_all, K_blk, V_blk, y_bf);

  gemm_bf16<<<dim3(16, 32), blk, 0, stream>>>(y_bf, 2048, Wo_bf, 2048, Wo_b, out, DM, DM, 2048);
}

// Round 8
// 476.725 us; speedup vs baseline: 12.9374x; 1.1831x over previous
//
#include <hip/hip_runtime.h>
#include <math.h>

#define TOK 4096
#define DM 2048
#define DQ 682
#define DQP 704
#define DKV 1024
#define DUKV 3072
#define NH 16
#define T_SEQ 2048
#define NQKV 1792   // 704 (padded Wdq) + 1088 (Wdkv)

typedef __attribute__((ext_vector_type(8))) short short8;
typedef __attribute__((ext_vector_type(4))) float floatx4;
typedef __attribute__((ext_vector_type(2))) unsigned int uint2v;

__device__ __forceinline__ unsigned short f2bf(float f) {
  union { float f; unsigned int u; } v; v.f = f;
  unsigned int u = v.u;
  u += 0x7fffu + ((u >> 16) & 1u);
  return (unsigned short)(u >> 16);
}
__device__ __forceinline__ unsigned short f2bf_fast(float f) {
  union { float f; unsigned int u; } v; v.f = f;
  return (unsigned short)((v.u + 0x8000u) >> 16);
}

typedef __attribute__((address_space(1))) const unsigned int as1_u32;
typedef __attribute__((address_space(3))) unsigned int as3_u32;
__device__ __forceinline__ void async16(const void* g, void* l) {
  __builtin_amdgcn_global_load_lds((as1_u32*)g, (as3_u32*)l, 16, 0, 0);
}

// ---------------------------------------------------------------------------
// bf16 MFMA GEMM (m97 structure), fp32 output. (verified R3-R7)
// ---------------------------------------------------------------------------
__global__ __launch_bounds__(256) void gemm_bf16(
    const unsigned short* __restrict__ A, int lda,
    const unsigned short* __restrict__ B, int ldb,
    const float* __restrict__ bias, float* __restrict__ C, int ldc,
    int Nvalid, int K)
{
  __shared__ __align__(16) unsigned short As[128 * 32];
  __shared__ __align__(16) unsigned short Bs[128 * 32];
  const int tid = threadIdx.x;
  const int w = tid >> 6;
  const int lane = tid & 63;
  const int q = lane >> 4;
  const int r = lane & 15;
  const int bm = blockIdx.y * 128;
  const int bn = blockIdx.x * 128;

  floatx4 acc[4][4];
#pragma unroll
  for (int i = 0; i < 4; i++)
#pragma unroll
    for (int j = 0; j < 4; j++) acc[i][j] = (floatx4){0.f, 0.f, 0.f, 0.f};

  const int srow = tid >> 2;
  const int scol = (tid & 3) * 8;
  const unsigned short* Ag0 = A + (size_t)(bm + srow) * lda + scol;
  const unsigned short* Ag1 = A + (size_t)(bm + 64 + srow) * lda + scol;
  const unsigned short* Bg0 = B + (size_t)(bn + srow) * ldb + scol;
  const unsigned short* Bg1 = B + (size_t)(bn + 64 + srow) * ldb + scol;
  unsigned short* AsL0 = &As[w * 512];
  unsigned short* AsL1 = &As[2048 + w * 512];
  unsigned short* BsL0 = &Bs[w * 512];
  unsigned short* BsL1 = &Bs[2048 + w * 512];

  const int mrow0 = (w >> 1) * 64;
  const int ncol0 = (w & 1) * 64;

  for (int k0 = 0; k0 < K; k0 += 32) {
    async16(Ag0 + k0, AsL0);
    async16(Ag1 + k0, AsL1);
    async16(Bg0 + k0, BsL0);
    async16(Bg1 + k0, BsL1);
    __syncthreads();
    short8 a[4], b[4];
#pragma unroll
    for (int i = 0; i < 4; i++)
      a[i] = *(const short8*)&As[(mrow0 + i * 16 + r) * 32 + q * 8];
#pragma unroll
    for (int j = 0; j < 4; j++)
      b[j] = *(const short8*)&Bs[(ncol0 + j * 16 + r) * 32 + q * 8];
#pragma unroll
    for (int i = 0; i < 4; i++)
#pragma unroll
      for (int j = 0; j < 4; j++)
        acc[i][j] = __builtin_amdgcn_mfma_f32_16x16x32_bf16(a[i], b[j], acc[i][j], 0, 0, 0);
    __syncthreads();
  }

#pragma unroll
  for (int j = 0; j < 4; j++) {
    int gc = bn + ncol0 + j * 16 + r;
    if (gc >= Nvalid) continue;
    float bv = bias[gc];
#pragma unroll
    for (int i = 0; i < 4; i++) {
#pragma unroll
      for (int v = 0; v < 4; v++) {
        int gr = bm + mrow0 + i * 16 + q * 4 + v;
        C[(size_t)gr * ldc + gc] = acc[i][j][v] + bv;
      }
    }
  }
}

// ---------------------------------------------------------------------------
// Same GEMM, bf16 output (for kv).
// ---------------------------------------------------------------------------
__global__ __launch_bounds__(256) void gemm_bf16_obf(
    const unsigned short* __restrict__ A, int lda,
    const unsigned short* __restrict__ B, int ldb,
    const float* __restrict__ bias, unsigned short* __restrict__ C, int ldc,
    int Nvalid, int K)
{
  __shared__ __align__(16) unsigned short As[128 * 32];
  __shared__ __align__(16) unsigned short Bs[128 * 32];
  const int tid = threadIdx.x;
  const int w = tid >> 6;
  const int lane = tid & 63;
  const int q = lane >> 4;
  const int r = lane & 15;
  const int bm = blockIdx.y * 128;
  const int bn = blockIdx.x * 128;

  floatx4 acc[4][4];
#pragma unroll
  for (int i = 0; i < 4; i++)
#pragma unroll
    for (int j = 0; j < 4; j++) acc[i][j] = (floatx4){0.f, 0.f, 0.f, 0.f};

  const int srow = tid >> 2;
  const int scol = (tid & 3) * 8;
  const unsigned short* Ag0 = A + (size_t)(bm + srow) * lda + scol;
  const unsigned short* Ag1 = A + (size_t)(bm + 64 + srow) * lda + scol;
  const unsigned short* Bg0 = B + (size_t)(bn + srow) * ldb + scol;
  const unsigned short* Bg1 = B + (size_t)(bn + 64 + srow) * ldb + scol;
  unsigned short* AsL0 = &As[w * 512];
  unsigned short* AsL1 = &As[2048 + w * 512];
  unsigned short* BsL0 = &Bs[w * 512];
  unsigned short* BsL1 = &Bs[2048 + w * 512];

  const int mrow0 = (w >> 1) * 64;
  const int ncol0 = (w & 1) * 64;

  for (int k0 = 0; k0 < K; k0 += 32) {
    async16(Ag0 + k0, AsL0);
    async16(Ag1 + k0, AsL1);
    async16(Bg0 + k0, BsL0);
    async16(Bg1 + k0, BsL1);
    __syncthreads();
    short8 a[4], b[4];
#pragma unroll
    for (int i = 0; i < 4; i++)
      a[i] = *(const short8*)&As[(mrow0 + i * 16 + r) * 32 + q * 8];
#pragma unroll
    for (int j = 0; j < 4; j++)
      b[j] = *(const short8*)&Bs[(ncol0 + j * 16 + r) * 32 + q * 8];
#pragma unroll
    for (int i = 0; i < 4; i++)
#pragma unroll
      for (int j = 0; j < 4; j++)
        acc[i][j] = __builtin_amdgcn_mfma_f32_16x16x32_bf16(a[i], b[j], acc[i][j], 0, 0, 0);
    __syncthreads();
  }

#pragma unroll
  for (int j = 0; j < 4; j++) {
    int gc = bn + ncol0 + j * 16 + r;
    if (gc >= Nvalid) continue;
    float bv = bias[gc];
#pragma unroll
    for (int i = 0; i < 4; i++) {
#pragma unroll
      for (int v = 0; v < 4; v++) {
        int gr = bm + mrow0 + i * 16 + q * 4 + v;
        C[(size_t)gr * ldc + gc] = f2bf(acc[i][j][v] + bv);
      }
    }
  }
}

// ---------------------------------------------------------------------------
// q-up GEMM with fused rotary + softmax-scale epilogue, bf16 Q_all output.
// N=2048 = 16 heads x 128; blockIdx.x == head. Rotary (reference quirk:
// angle = h * 10000^(-jj/32)) pairs cols d and d+32, which live in the SAME
// thread (acc cols j and j+2). QS = scale*log2(e) folded for exp2 softmax.
// ---------------------------------------------------------------------------
__global__ __launch_bounds__(256) void gemm_qrope(
    const unsigned short* __restrict__ A, int lda,
    const unsigned short* __restrict__ B, int ldb,
    const float* __restrict__ bias, unsigned short* __restrict__ Qall, int K)
{
  __shared__ __align__(16) unsigned short As[128 * 32];
  __shared__ __align__(16) unsigned short Bs[128 * 32];
  const int tid = threadIdx.x;
  const int w = tid >> 6;
  const int lane = tid & 63;
  const int q = lane >> 4;
  const int r = lane & 15;
  const int bm = blockIdx.y * 128;
  const int bn = blockIdx.x * 128;
  const int h = blockIdx.x;

  floatx4 acc[4][4];
#pragma unroll
  for (int i = 0; i < 4; i++)
#pragma unroll
    for (int j = 0; j < 4; j++) acc[i][j] = (floatx4){0.f, 0.f, 0.f, 0.f};

  const int srow = tid >> 2;
  const int scol = (tid & 3) * 8;
  const unsigned short* Ag0 = A + (size_t)(bm + srow) * lda + scol;
  const unsigned short* Ag1 = A + (size_t)(bm + 64 + srow) * lda + scol;
  const unsigned short* Bg0 = B + (size_t)(bn + srow) * ldb + scol;
  const unsigned short* Bg1 = B + (size_t)(bn + 64 + srow) * ldb + scol;
  unsigned short* AsL0 = &As[w * 512];
  unsigned short* AsL1 = &As[2048 + w * 512];
  unsigned short* BsL0 = &Bs[w * 512];
  unsigned short* BsL1 = &Bs[2048 + w * 512];

  const int mrow0 = (w >> 1) * 64;
  const int ncol0 = (w & 1) * 64;

  for (int k0 = 0; k0 < K; k0 += 32) {
    async16(Ag0 + k0, AsL0);
    async16(Ag1 + k0, AsL1);
    async16(Bg0 + k0, BsL0);
    async16(Bg1 + k0, BsL1);
    __syncthreads();
    short8 a[4], b[4];
#pragma unroll
    for (int i = 0; i < 4; i++)
      a[i] = *(const short8*)&As[(mrow0 + i * 16 + r) * 32 + q * 8];
#pragma unroll
    for (int j = 0; j < 4; j++)
      b[j] = *(const short8*)&Bs[(ncol0 + j * 16 + r) * 32 + q * 8];
#pragma unroll
    for (int i = 0; i < 4; i++)
#pragma unroll
      for (int j = 0; j < 4; j++)
        acc[i][j] = __builtin_amdgcn_mfma_f32_16x16x32_bf16(a[i], b[j], acc[i][j], 0, 0, 0);
    __syncthreads();
  }

  const float QS = (float)(0.08838834764831845 * 1.4426950408889634);
  if ((w & 1) == 0) {
    // d in [0,64): no rotary
#pragma unroll
    for (int j = 0; j < 4; j++) {
      int d = j * 16 + r;
      float bv = bias[h * 128 + d];
#pragma unroll
      for (int i = 0; i < 4; i++) {
#pragma unroll
        for (int v = 0; v < 4; v++) {
          int gr = bm + mrow0 + i * 16 + q * 4 + v;
          int bb = gr >> 11, t = gr & 2047;
          Qall[(((size_t)(bb * NH + h)) * T_SEQ + t) * 128 + d] =
              f2bf((acc[i][j][v] + bv) * QS);
        }
      }
    }
  } else {
    // d in [64,128): rotary pairs (64+jj, 96+jj); jj = jp*16 + r
    float cs[2], sn[2], bv1[2], bv2[2];
#pragma unroll
    for (int jp = 0; jp < 2; jp++) {
      int jj = jp * 16 + r;
      float ang = (float)h * exp2f(-(float)jj * (13.287712379549449f / 32.0f));
      cs[jp] = cosf(ang); sn[jp] = sinf(ang);
      bv1[jp] = bias[h * 128 + 64 + jj];
      bv2[jp] = bias[h * 128 + 96 + jj];
    }
#pragma unroll
    for (int i = 0; i < 4; i++) {
#pragma unroll
      for (int v = 0; v < 4; v++) {
        int gr = bm + mrow0 + i * 16 + q * 4 + v;
        int bb = gr >> 11, t = gr & 2047;
        unsigned short* Qr = Qall + (((size_t)(bb * NH + h)) * T_SEQ + t) * 128;
#pragma unroll
        for (int jp = 0; jp < 2; jp++) {
          int jj = jp * 16 + r;
          float x1 = acc[i][jp][v] + bv1[jp];
          float x2 = acc[i][jp + 2][v] + bv2[jp];
          Qr[64 + jj] = f2bf((x1 * cs[jp] + x2 * sn[jp]) * QS);
          Qr[96 + jj] = f2bf((x2 * cs[jp] - x1 * sn[jp]) * QS);
        }
      }
    }
  }
}

// ---------------------------------------------------------------------------
__global__ __launch_bounds__(256) void cvt_bf16_pad(
    const float* __restrict__ in, unsigned short* __restrict__ out,
    int irows, int icols, int ocols, long total)
{
  long idx = (long)blockIdx.x * 256 + threadIdx.x;
  if (idx >= total) return;
  int rr = (int)(idx / ocols);
  int cc = (int)(idx - (long)rr * ocols);
  out[idx] = (rr < irows && cc < icols) ? f2bf(in[(size_t)rr * icols + cc]) : 0;
}

// bias_qkv[1792] = [Wdq_b (682), 0 (22), Wdkv_b (1088)]
__global__ __launch_bounds__(256) void bias_concat(
    const float* __restrict__ a, const float* __restrict__ b,
    float* __restrict__ out)
{
  int i = blockIdx.x * 256 + threadIdx.x;
  if (i >= NQKV) return;
  out[i] = (i < DQ) ? a[i] : ((i < DQP) ? 0.f : b[i - DQP]);
}

// ---------------------------------------------------------------------------
__device__ __forceinline__ float block_sum(float v, float* sbuf) {
#pragma unroll
  for (int off = 32; off > 0; off >>= 1) v += __shfl_down(v, off, 64);
  int wid = threadIdx.x >> 6;
  __syncthreads();
  if ((threadIdx.x & 63) == 0) sbuf[wid] = v;
  __syncthreads();
  return sbuf[0] + sbuf[1] + sbuf[2] + sbuf[3];
}

__global__ __launch_bounds__(256) void ln_bf16_kernel(
    const float* __restrict__ in, int istride,
    unsigned short* __restrict__ out, int ocols,
    const float* __restrict__ g, const float* __restrict__ bta, int D)
{
  __shared__ float sbuf[4];
  size_t row = blockIdx.x;
  const float* xr = in + row * istride;
  float s = 0.f;
  for (int i = threadIdx.x; i < D; i += 256) s += xr[i];
  float mu = block_sum(s, sbuf) / (float)D;
  float v = 0.f;
  for (int i = threadIdx.x; i < D; i += 256) { float d = xr[i] - mu; v += d * d; }
  float var = block_sum(v, sbuf) / (float)D;
  float rstd = rsqrtf(var + 1e-5f);
  unsigned short* orow = out + row * ocols;
  for (int i = threadIdx.x; i < ocols; i += 256)
    orow[i] = (i < D) ? f2bf((xr[i] - mu) * rstd * g[i] + bta[i]) : 0;
}

// ---------------------------------------------------------------------------
// K_blk: per (bh, kt) contiguous 8192-elem tile [c=4][row64][32] (attention
// LDS image). d<64 from kv_bf (k_n); d>=64 from c_qkv cols 1728.. (k rotary
// identity per reference quirk). c_qkv stride NQKV.
// ---------------------------------------------------------------------------
__global__ __launch_bounds__(256) void repack_k_blk(
    const unsigned short* __restrict__ kv_bf, const float* __restrict__ cqkv,
    unsigned short* __restrict__ K)
{
  int idx = blockIdx.x * 256 + threadIdx.x;
  int dlow = idx & 31;
  int tt   = (idx >> 5) & 63;
  int dhi  = (idx >> 11) & 3;
  int kt   = (idx >> 13) & 31;
  int bh   = idx >> 18;
  int d = dhi * 32 + dlow;
  int t = kt * 64 + tt;
  int b = bh >> 4, h = bh & 15;
  unsigned short val;
  if (d < 64)
    val = kv_bf[((size_t)(b * T_SEQ + t)) * DUKV + h * 192 + d];
  else
    val = f2bf(cqkv[((size_t)(b * T_SEQ + t)) * NQKV + 1728 + (d - 64)]);
  K[idx] = val;
}

// ---------------------------------------------------------------------------
// V_blk: per (bh, kt) contiguous 8192-elem tile [c2=2][d128][32] = V^T image.
// ---------------------------------------------------------------------------
__global__ __launch_bounds__(256) void repack_v_blk(
    const unsigned short* __restrict__ kv_bf, unsigned short* __restrict__ V)
{
  __shared__ unsigned short T[64 * 132];
  int kt = blockIdx.x, bh = blockIdx.y;
  int b = bh >> 4, h = bh & 15;
  int tid = threadIdx.x;
#pragma unroll
  for (int p = 0; p < 8; p++) {
    int t = p * 8 + (tid >> 5);
    int dbase = (tid & 31) * 4;
    const unsigned short* src =
        kv_bf + ((size_t)(b * T_SEQ + kt * 64 + t)) * DUKV + h * 192 + 64 + dbase;
    unsigned short v0 = src[0], v1 = src[1], v2 = src[2], v3 = src[3];
    unsigned short* dst = &T[t * 132 + dbase];
    dst[0] = v0; dst[1] = v1; dst[2] = v2; dst[3] = v3;
  }
  __syncthreads();
  unsigned short* out = V + ((size_t)(bh * 32 + kt)) * 8192;
#pragma unroll
  for (int p = 0; p < 4; p++) {
    int o = p * 2048 + tid * 8;
    int c2 = o >> 12;
    int dd = (o >> 5) & 127;
    int tl = o & 31;
    short8 pack;
#pragma unroll
    for (int i = 0; i < 8; i++)
      pack[i] = (short)T[(c2 * 32 + tl + i) * 132 + dd];
    *(short8*)&out[o] = pack;
  }
}

// ---------------------------------------------------------------------------
// attn v3b: S^T-form MFMA flash attention, 128-row Q tiles, K/V double-buffer
// prefetch. LOAD-BALANCE FIX (R7->R8): qt = z ? 15-x : x, so the two blocks a
// CU receives (bid, bid+256 differ only in z) have complementary work:
// (2qt+2) + (2(15-qt)+2) = 34 iters, constant across CUs.
// Ps stores packed as 8-byte writes.
// ---------------------------------------------------------------------------
__global__ __launch_bounds__(256, 2) void attn_mfma3(
    const unsigned short* __restrict__ Qall,
    const unsigned short* __restrict__ Kblk,
    const unsigned short* __restrict__ Vblk,
    unsigned short* __restrict__ y)
{
  __shared__ __align__(16) unsigned short sm[37376];
  const int x = (int)blockIdx.x;
  const int b = (int)blockIdx.z;
  const int qt = b ? (15 - x) : x;
  const int h = blockIdx.y;
  const int tid = threadIdx.x;
  const int w = tid >> 6, lane = tid & 63, q = lane >> 4, r = lane & 15;
  const int bh = b * NH + h;

  short8 qb[2][4];
#pragma unroll
  for (int g = 0; g < 2; g++) {
    const unsigned short* Qrow =
        Qall + ((size_t)bh * T_SEQ + (size_t)qt * 128 + w * 32 + g * 16 + r) * 128 + q * 8;
#pragma unroll
    for (int c = 0; c < 4; c++) qb[g][c] = *(const short8*)(Qrow + c * 32);
  }

  floatx4 oacc[2][8];
#pragma unroll
  for (int g = 0; g < 2; g++)
#pragma unroll
    for (int jd = 0; jd < 8; jd++) oacc[g][jd] = (floatx4){0.f, 0.f, 0.f, 0.f};
  float m_i[2] = {-3.0e38f, -3.0e38f}, l_i[2] = {0.f, 0.f};

  const char* Kg0 = (const char*)(Kblk + ((size_t)(bh * 32)) * 8192);
  const char* Vg0 = (const char*)(Vblk + ((size_t)(bh * 32)) * 8192);
  char* smB = (char*)sm;
  unsigned short* Psw = sm + 32768 + w * 1152;
  const int ktmax = 2 * qt + 1;

#pragma unroll
  for (int i = 0; i < 4; i++) {
    async16(Kg0 + i * 4096 + w * 1024 + lane * 16, smB + i * 4096 + w * 1024);
    async16(Vg0 + i * 4096 + w * 1024 + lane * 16, smB + 32768 + i * 4096 + w * 1024);
  }

  for (int kt = 0; kt <= ktmax; kt++) {
    const int cur = kt & 1;
    __syncthreads();
    if (kt < ktmax) {
      const int nxt = cur ^ 1;
      const char* Kg = Kg0 + (size_t)(kt + 1) * 16384;
      const char* Vg = Vg0 + (size_t)(kt + 1) * 16384;
#pragma unroll
      for (int i = 0; i < 4; i++) {
        async16(Kg + i * 4096 + w * 1024 + lane * 16,
                smB + nxt * 16384 + i * 4096 + w * 1024);
        async16(Vg + i * 4096 + w * 1024 + lane * 16,
                smB + 32768 + nxt * 16384 + i * 4096 + w * 1024);
      }
    }

    const bool activeW = (kt * 64 <= qt * 128 + w * 32 + 31);
    if (activeW) {
      const unsigned short* KsC = sm + cur * 8192;
      const unsigned short* VsC = sm + 16384 + cur * 8192;

      floatx4 sacc[2][4];
#pragma unroll
      for (int g = 0; g < 2; g++)
#pragma unroll
        for (int j = 0; j < 4; j++) sacc[g][j] = (floatx4){0.f, 0.f, 0.f, 0.f};
#pragma unroll
      for (int c = 0; c < 4; c++) {
        short8 ak[4];
#pragma unroll
        for (int j = 0; j < 4; j++)
          ak[j] = *(const short8*)&KsC[c * 2048 + (j * 16 + r) * 32 + q * 8];
#pragma unroll
        for (int g = 0; g < 2; g++)
#pragma unroll
          for (int j = 0; j < 4; j++)
            sacc[g][j] = __builtin_amdgcn_mfma_f32_16x16x32_bf16(ak[j], qb[g][c], sacc[g][j], 0, 0, 0);
      }

#pragma unroll
      for (int g = 0; g < 2; g++) {
        float sv[16];
#pragma unroll
        for (int j = 0; j < 4; j++)
#pragma unroll
          for (int v = 0; v < 4; v++) sv[j * 4 + v] = sacc[g][j][v];
        const int rel = qt * 128 + w * 32 + g * 16 + r - kt * 64;
        if (rel < 63) {
#pragma unroll
          for (int j = 0; j < 4; j++)
#pragma unroll
            for (int v = 0; v < 4; v++)
              if (j * 16 + q * 4 + v > rel) sv[j * 4 + v] = -3.0e38f;
        }
        float rm = sv[0];
#pragma unroll
        for (int t16 = 1; t16 < 16; t16++) rm = fmaxf(rm, sv[t16]);
        rm = fmaxf(rm, __shfl_xor(rm, 16, 64));
        rm = fmaxf(rm, __shfl_xor(rm, 32, 64));
        float mnew = fmaxf(m_i[g], rm);
        float alpha = exp2f(m_i[g] - mnew);
        m_i[g] = mnew;
        float p[16], rsum = 0.f;
#pragma unroll
        for (int t16 = 0; t16 < 16; t16++) { p[t16] = exp2f(sv[t16] - mnew); rsum += p[t16]; }
        rsum += __shfl_xor(rsum, 16, 64);
        rsum += __shfl_xor(rsum, 32, 64);
        l_i[g] = l_i[g] * alpha + rsum;
#pragma unroll
        for (int jd = 0; jd < 8; jd++) {
          oacc[g][jd][0] *= alpha; oacc[g][jd][1] *= alpha;
          oacc[g][jd][2] *= alpha; oacc[g][jd][3] *= alpha;
        }
#pragma unroll
        for (int j = 0; j < 4; j++) {
          unsigned int lo = (unsigned int)f2bf_fast(p[j * 4 + 0]) |
                            ((unsigned int)f2bf_fast(p[j * 4 + 1]) << 16);
          unsigned int hi = (unsigned int)f2bf_fast(p[j * 4 + 2]) |
                            ((unsigned int)f2bf_fast(p[j * 4 + 3]) << 16);
          uint2v pk; pk[0] = lo; pk[1] = hi;
          *(uint2v*)&Psw[r * 72 + j * 16 + q * 4] = pk;
        }
#pragma unroll
        for (int c2 = 0; c2 < 2; c2++) {
          short8 pb = *(const short8*)&Psw[r * 72 + c2 * 32 + q * 8];
#pragma unroll
          for (int jd = 0; jd < 8; jd++) {
            short8 bv = *(const short8*)&VsC[c2 * 4096 + (jd * 16 + r) * 32 + q * 8];
            oacc[g][jd] = __builtin_amdgcn_mfma_f32_16x16x32_bf16(bv, pb, oacc[g][jd], 0, 0, 0);
          }
        }
      }
    }
  }

#pragma unroll
  for (int g = 0; g < 2; g++) {
    float inv = 1.0f / l_i[g];
    unsigned short* yr =
        y + ((size_t)(b * T_SEQ) + (size_t)qt * 128 + w * 32 + g * 16 + r) * DM + h * 128;
#pragma unroll
    for (int jd = 0; jd < 8; jd++) {
      unsigned short o0 = f2bf(oacc[g][jd][0] * inv);
      unsigned short o1 = f2bf(oacc[g][jd][1] * inv);
      unsigned short o2 = f2bf(oacc[g][jd][2] * inv);
      unsigned short o3 = f2bf(oacc[g][jd][3] * inv);
      unsigned int lo = (unsigned int)o0 | ((unsigned int)o1 << 16);
      unsigned int hi = (unsigned int)o2 | ((unsigned int)o3 << 16);
      unsigned int* dst = (unsigned int*)(yr + jd * 16 + q * 4);
      dst[0] = lo; dst[1] = hi;
    }
  }
}

// ---------------------------------------------------------------------------
extern "C" void kernel_launch(void* const* d_in, const int* in_sizes, int n_in,
                              void* d_out, int out_size, void* d_ws, size_t ws_size,
                              hipStream_t stream) {
  const float* x      = (const float*)d_in[0];
  const float* Wdq_w  = (const float*)d_in[1];
  const float* Wdq_b  = (const float*)d_in[2];
  const float* qn_g   = (const float*)d_in[3];
  const float* qn_b   = (const float*)d_in[4];
  const float* Wuq_w  = (const float*)d_in[5];
  const float* Wuq_b  = (const float*)d_in[6];
  const float* Wdkv_w = (const float*)d_in[7];
  const float* Wdkv_b = (const float*)d_in[8];
  const float* kvn_g  = (const float*)d_in[9];
  const float* kvn_b  = (const float*)d_in[10];
  const float* Wukv_w = (const float*)d_in[11];
  const float* Wukv_b = (const float*)d_in[12];
  const float* Wo_w   = (const float*)d_in[13];
  const float* Wo_b   = (const float*)d_in[14];
  float* out = (float*)d_out;

  float* ws = (float*)d_ws;
  // float-unit offsets
  unsigned short* x_bf    = (unsigned short*)(ws);              // [0, 4194304) dies after c_qkv gemm
  unsigned short* y_bf    = (unsigned short*)(ws);              // alias: attn output
  unsigned short* Wqkv_bf = (unsigned short*)(ws + 4194304);    // 1792x2048
  unsigned short* Wuq_bf  = (unsigned short*)(ws + 6029312);    // 2048x704
  unsigned short* Wukv_bf = (unsigned short*)(ws + 6750208);    // 3072x1024
  float* bias_qkv = ws + 8323072;                               // 1792
  float* c_qkv    = ws + 8324864;                               // 4096x1792 fp32
  unsigned short* c_q_bf = (unsigned short*)(ws + 15664896);    // 4096x704
  unsigned short* kvn_bf = (unsigned short*)(ws + 17106688);    // 4096x1024
  unsigned short* kv_bf  = (unsigned short*)(ws + 19203840);    // 4096x3072
  unsigned short* Q_all  = (unsigned short*)(ws + 25495296);    // 2x16x2048x128
  unsigned short* K_blk  = (unsigned short*)(ws + 29689600);
  unsigned short* V_blk  = (unsigned short*)(ws + 33883904);
  unsigned short* Wo_bf  = (unsigned short*)(ws + 38078208);    // 2048x2048

  dim3 blk(256);

  cvt_bf16_pad<<<(4096L*2048 + 255) / 256, blk, 0, stream>>>(x, x_bf, 4096, 2048, 2048, 4096L*2048);
  cvt_bf16_pad<<<(704L*2048 + 255) / 256, blk, 0, stream>>>(Wdq_w, Wqkv_bf, 682, 2048, 2048, 704L*2048);
  cvt_bf16_pad<<<(1088L*2048 + 255) / 256, blk, 0, stream>>>(Wdkv_w, Wqkv_bf + 704L*2048, 1088, 2048, 2048, 1088L*2048);
  cvt_bf16_pad<<<(2048L*704 + 255) / 256, blk, 0, stream>>>(Wuq_w, Wuq_bf, 2048, 682, 704, 2048L*704);
  cvt_bf16_pad<<<(3072L*1024 + 255) / 256, blk, 0, stream>>>(Wukv_w, Wukv_bf, 3072, 1024, 1024, 3072L*1024);
  cvt_bf16_pad<<<(2048L*2048 + 255) / 256, blk, 0, stream>>>(Wo_w, Wo_bf, 2048, 2048, 2048, 2048L*2048);
  bias_concat<<<7, blk, 0, stream>>>(Wdq_b, Wdkv_b, bias_qkv);

  // merged c_qkv = x @ [Wdq; Wdkv]^T + bias   (N=1792, 448 blocks)
  gemm_bf16<<<dim3(14, 32), blk, 0, stream>>>(x_bf, 2048, Wqkv_bf, 2048, bias_qkv, c_qkv, NQKV, NQKV, 2048);
  // LN q: cols [0,682) ; LN kv: cols [704, 1728)
  ln_bf16_kernel<<<TOK, blk, 0, stream>>>(c_qkv, NQKV, c_q_bf, DQP, qn_g, qn_b, DQ);
  ln_bf16_kernel<<<TOK, blk, 0, stream>>>(c_qkv + DQP, NQKV, kvn_bf, DKV, kvn_g, kvn_b, DKV);
  // q-up GEMM with fused rotary -> Q_all bf16
  gemm_qrope<<<dim3(16, 32), blk, 0, stream>>>(c_q_bf, DQP, Wuq_bf, DQP, Wuq_b, Q_all, DQP);
  // kv-up GEMM -> bf16
  gemm_bf16_obf<<<dim3(24, 32), blk, 0, stream>>>(kvn_bf, DKV, Wukv_bf, DKV, Wukv_b, kv_bf, DUKV, DUKV, DKV);
  // K/V tile caches
  repack_k_blk<<<(2 * NH * T_SEQ * 128) / 256, blk, 0, stream>>>(kv_bf, c_qkv, K_blk);
  repack_v_blk<<<dim3(32, 32), blk, 0, stream>>>(kv_bf, V_blk);
  // attention
  attn_mfma3<<<dim3(16, 16, 2), blk, 0, stream>>>(Q_all, K_blk, V_blk, y_bf);
  // out = y @ Wo^T + b
  gemm_bf16<<<dim3(16, 32), blk, 0, stream>>>(y_bf, 2048, Wo_bf, 2048, Wo_b, out, DM, DM, 2048);
}

// Round 9
// 426.850 us; speedup vs baseline: 14.4490x; 1.1168x over previous
//
#include <hip/hip_runtime.h>
#include <math.h>

#define TOK 4096
#define DM 2048
#define DQ 682
#define DQP 704
#define DKV 1024
#define DUKV 3072
#define NH 16
#define T_SEQ 2048
#define NQKV 1792   // 704 (padded Wdq) + 1088 (Wdkv)

typedef __attribute__((ext_vector_type(8))) short short8;
typedef __attribute__((ext_vector_type(4))) float floatx4;
typedef __attribute__((ext_vector_type(2))) unsigned int uint2v;

__device__ __forceinline__ unsigned short f2bf(float f) {
  union { float f; unsigned int u; } v; v.f = f;
  unsigned int u = v.u;
  u += 0x7fffu + ((u >> 16) & 1u);
  return (unsigned short)(u >> 16);
}
__device__ __forceinline__ unsigned short f2bf_fast(float f) {
  union { float f; unsigned int u; } v; v.f = f;
  return (unsigned short)((v.u + 0x8000u) >> 16);
}

typedef __attribute__((address_space(1))) const unsigned int as1_u32;
typedef __attribute__((address_space(3))) unsigned int as3_u32;
__device__ __forceinline__ void async16(const void* g, void* l) {
  __builtin_amdgcn_global_load_lds((as1_u32*)g, (as3_u32*)l, 16, 0, 0);
}

// ---------------------------------------------------------------------------
// bf16 MFMA GEMM, double-buffered K-loop (attn_mfma3-validated pipeline:
// one barrier/iter; prefetch for k+1 issued right after the barrier so the
// vmcnt(0) drain lands a full compute phase later). fp32 output + bias.
// LDS 32KB (2x(As+Bs)).
// ---------------------------------------------------------------------------
__global__ __launch_bounds__(256) void gemm_bf16_db(
    const unsigned short* __restrict__ A, int lda,
    const unsigned short* __restrict__ B, int ldb,
    const float* __restrict__ bias, float* __restrict__ C, int ldc,
    int Nvalid, int K)
{
  __shared__ __align__(16) unsigned short sm[16384]; // As0,As1,Bs0,Bs1 x4096
  const int tid = threadIdx.x;
  const int w = tid >> 6;
  const int lane = tid & 63;
  const int q = lane >> 4;
  const int r = lane & 15;
  const int bm = blockIdx.y * 128;
  const int bn = blockIdx.x * 128;

  floatx4 acc[4][4];
#pragma unroll
  for (int i = 0; i < 4; i++)
#pragma unroll
    for (int j = 0; j < 4; j++) acc[i][j] = (floatx4){0.f, 0.f, 0.f, 0.f};

  const int srow = tid >> 2;
  const int scol = (tid & 3) * 8;
  const unsigned short* Ag0 = A + (size_t)(bm + srow) * lda + scol;
  const unsigned short* Ag1 = A + (size_t)(bm + 64 + srow) * lda + scol;
  const unsigned short* Bg0 = B + (size_t)(bn + srow) * ldb + scol;
  const unsigned short* Bg1 = B + (size_t)(bn + 64 + srow) * ldb + scol;

  const int mrow0 = (w >> 1) * 64;
  const int ncol0 = (w & 1) * 64;

  // prologue: stage k0=0 into buffer 0
  async16(Ag0, &sm[w * 512]);
  async16(Ag1, &sm[2048 + w * 512]);
  async16(Bg0, &sm[8192 + w * 512]);
  async16(Bg1, &sm[8192 + 2048 + w * 512]);

  for (int k0 = 0; k0 < K; k0 += 32) {
    const int cur = (k0 >> 5) & 1;
    __syncthreads();  // drains loads for cur; all waves done reading buf nxt
    if (k0 + 32 < K) {
      const int nxt = cur ^ 1;
      async16(Ag0 + k0 + 32, &sm[nxt * 4096 + w * 512]);
      async16(Ag1 + k0 + 32, &sm[nxt * 4096 + 2048 + w * 512]);
      async16(Bg0 + k0 + 32, &sm[8192 + nxt * 4096 + w * 512]);
      async16(Bg1 + k0 + 32, &sm[8192 + nxt * 4096 + 2048 + w * 512]);
    }
    const unsigned short* As = &sm[cur * 4096];
    const unsigned short* Bs = &sm[8192 + cur * 4096];
    short8 a[4], b[4];
#pragma unroll
    for (int i = 0; i < 4; i++)
      a[i] = *(const short8*)&As[(mrow0 + i * 16 + r) * 32 + q * 8];
#pragma unroll
    for (int j = 0; j < 4; j++)
      b[j] = *(const short8*)&Bs[(ncol0 + j * 16 + r) * 32 + q * 8];
#pragma unroll
    for (int i = 0; i < 4; i++)
#pragma unroll
      for (int j = 0; j < 4; j++)
        acc[i][j] = __builtin_amdgcn_mfma_f32_16x16x32_bf16(a[i], b[j], acc[i][j], 0, 0, 0);
  }

#pragma unroll
  for (int j = 0; j < 4; j++) {
    int gc = bn + ncol0 + j * 16 + r;
    if (gc >= Nvalid) continue;
    float bv = bias[gc];
#pragma unroll
    for (int i = 0; i < 4; i++) {
#pragma unroll
      for (int v = 0; v < 4; v++) {
        int gr = bm + mrow0 + i * 16 + q * 4 + v;
        C[(size_t)gr * ldc + gc] = acc[i][j][v] + bv;
      }
    }
  }
}

// ---------------------------------------------------------------------------
// Fused up-projection GEMM (double-buffered): one launch covers BOTH
//   bx <  16: q-up with fused rotary+scale epilogue -> Q_all bf16 (h = bx)
//   bx >= 16: kv-up -> kv_bf bf16 (ldc 3072)
// 1280 blocks total (5/CU) instead of two serialized low-occupancy launches.
// ---------------------------------------------------------------------------
__global__ __launch_bounds__(256) void gemm_up_fused(
    const unsigned short* __restrict__ Aq, const unsigned short* __restrict__ Bq,
    const float* __restrict__ biasq, unsigned short* __restrict__ Qall,
    const unsigned short* __restrict__ Akv, const unsigned short* __restrict__ Bkv,
    const float* __restrict__ biaskv, unsigned short* __restrict__ kvout)
{
  __shared__ __align__(16) unsigned short sm[16384];
  const int tid = threadIdx.x;
  const int w = tid >> 6;
  const int lane = tid & 63;
  const int q = lane >> 4;
  const int r = lane & 15;
  const int bx = blockIdx.x;
  const bool isQ = bx < 16;
  const int bn = isQ ? bx * 128 : (bx - 16) * 128;
  const int bm = blockIdx.y * 128;
  const int K = isQ ? DQP : DKV;
  const unsigned short* A = isQ ? Aq : Akv;
  const unsigned short* B = isQ ? Bq : Bkv;

  floatx4 acc[4][4];
#pragma unroll
  for (int i = 0; i < 4; i++)
#pragma unroll
    for (int j = 0; j < 4; j++) acc[i][j] = (floatx4){0.f, 0.f, 0.f, 0.f};

  const int srow = tid >> 2;
  const int scol = (tid & 3) * 8;
  const unsigned short* Ag0 = A + (size_t)(bm + srow) * K + scol;
  const unsigned short* Ag1 = A + (size_t)(bm + 64 + srow) * K + scol;
  const unsigned short* Bg0 = B + (size_t)(bn + srow) * K + scol;
  const unsigned short* Bg1 = B + (size_t)(bn + 64 + srow) * K + scol;

  const int mrow0 = (w >> 1) * 64;
  const int ncol0 = (w & 1) * 64;

  async16(Ag0, &sm[w * 512]);
  async16(Ag1, &sm[2048 + w * 512]);
  async16(Bg0, &sm[8192 + w * 512]);
  async16(Bg1, &sm[8192 + 2048 + w * 512]);

  for (int k0 = 0; k0 < K; k0 += 32) {
    const int cur = (k0 >> 5) & 1;
    __syncthreads();
    if (k0 + 32 < K) {
      const int nxt = cur ^ 1;
      async16(Ag0 + k0 + 32, &sm[nxt * 4096 + w * 512]);
      async16(Ag1 + k0 + 32, &sm[nxt * 4096 + 2048 + w * 512]);
      async16(Bg0 + k0 + 32, &sm[8192 + nxt * 4096 + w * 512]);
      async16(Bg1 + k0 + 32, &sm[8192 + nxt * 4096 + 2048 + w * 512]);
    }
    const unsigned short* As = &sm[cur * 4096];
    const unsigned short* Bs = &sm[8192 + cur * 4096];
    short8 a[4], b[4];
#pragma unroll
    for (int i = 0; i < 4; i++)
      a[i] = *(const short8*)&As[(mrow0 + i * 16 + r) * 32 + q * 8];
#pragma unroll
    for (int j = 0; j < 4; j++)
      b[j] = *(const short8*)&Bs[(ncol0 + j * 16 + r) * 32 + q * 8];
#pragma unroll
    for (int i = 0; i < 4; i++)
#pragma unroll
      for (int j = 0; j < 4; j++)
        acc[i][j] = __builtin_amdgcn_mfma_f32_16x16x32_bf16(a[i], b[j], acc[i][j], 0, 0, 0);
  }

  if (!isQ) {
    // kv epilogue: bf16 to kvout[4096][3072]
#pragma unroll
    for (int j = 0; j < 4; j++) {
      int gc = bn + ncol0 + j * 16 + r;
      float bv = biaskv[gc];
#pragma unroll
      for (int i = 0; i < 4; i++) {
#pragma unroll
        for (int v = 0; v < 4; v++) {
          int gr = bm + mrow0 + i * 16 + q * 4 + v;
          kvout[(size_t)gr * DUKV + gc] = f2bf(acc[i][j][v] + bv);
        }
      }
    }
    return;
  }

  // q epilogue: fused rotary (reference quirk: angle = h * 10000^(-jj/32),
  // pairs cols d,d+32 in same thread) + softmax scale*log2e -> Q_all bf16.
  const int h = bx;
  const float QS = (float)(0.08838834764831845 * 1.4426950408889634);
  if ((w & 1) == 0) {
#pragma unroll
    for (int j = 0; j < 4; j++) {
      int d = j * 16 + r;
      float bv = biasq[h * 128 + d];
#pragma unroll
      for (int i = 0; i < 4; i++) {
#pragma unroll
        for (int v = 0; v < 4; v++) {
          int gr = bm + mrow0 + i * 16 + q * 4 + v;
          int bb = gr >> 11, t = gr & 2047;
          Qall[(((size_t)(bb * NH + h)) * T_SEQ + t) * 128 + d] =
              f2bf((acc[i][j][v] + bv) * QS);
        }
      }
    }
  } else {
    float cs[2], sn[2], bv1[2], bv2[2];
#pragma unroll
    for (int jp = 0; jp < 2; jp++) {
      int jj = jp * 16 + r;
      float ang = (float)h * exp2f(-(float)jj * (13.287712379549449f / 32.0f));
      cs[jp] = cosf(ang); sn[jp] = sinf(ang);
      bv1[jp] = biasq[h * 128 + 64 + jj];
      bv2[jp] = biasq[h * 128 + 96 + jj];
    }
#pragma unroll
    for (int i = 0; i < 4; i++) {
#pragma unroll
      for (int v = 0; v < 4; v++) {
        int gr = bm + mrow0 + i * 16 + q * 4 + v;
        int bb = gr >> 11, t = gr & 2047;
        unsigned short* Qr = Qall + (((size_t)(bb * NH + h)) * T_SEQ + t) * 128;
#pragma unroll
        for (int jp = 0; jp < 2; jp++) {
          int jj = jp * 16 + r;
          float x1 = acc[i][jp][v] + bv1[jp];
          float x2 = acc[i][jp + 2][v] + bv2[jp];
          Qr[64 + jj] = f2bf((x1 * cs[jp] + x2 * sn[jp]) * QS);
          Qr[96 + jj] = f2bf((x2 * cs[jp] - x1 * sn[jp]) * QS);
        }
      }
    }
  }
}

// ---------------------------------------------------------------------------
__global__ __launch_bounds__(256) void cvt_bf16_pad(
    const float* __restrict__ in, unsigned short* __restrict__ out,
    int irows, int icols, int ocols, long total)
{
  long idx = (long)blockIdx.x * 256 + threadIdx.x;
  if (idx >= total) return;
  int rr = (int)(idx / ocols);
  int cc = (int)(idx - (long)rr * ocols);
  out[idx] = (rr < irows && cc < icols) ? f2bf(in[(size_t)rr * icols + cc]) : 0;
}

// ---------------------------------------------------------------------------
// All 5 weight conversions + bias concat in ONE launch (block-range dispatch).
// ---------------------------------------------------------------------------
__device__ __forceinline__ void cvt_region(
    const float* __restrict__ in, unsigned short* __restrict__ out,
    int irows, int icols, int ocols, long idx)
{
  int rr = (int)(idx / ocols);
  int cc = (int)(idx - (long)rr * ocols);
  out[idx] = (rr < irows && cc < icols) ? f2bf(in[(size_t)rr * icols + cc]) : 0;
}

__global__ __launch_bounds__(256) void prep_weights(
    const float* __restrict__ Wdq_w, const float* __restrict__ Wdkv_w,
    const float* __restrict__ Wuq_w, const float* __restrict__ Wukv_w,
    const float* __restrict__ Wo_w,
    const float* __restrict__ Wdq_b, const float* __restrict__ Wdkv_b,
    unsigned short* __restrict__ Wqkv_bf, unsigned short* __restrict__ Wuq_bf,
    unsigned short* __restrict__ Wukv_bf, unsigned short* __restrict__ Wo_bf,
    float* __restrict__ bias_qkv)
{
  const long bx = blockIdx.x;
  if (bx < 5632) {                      // Wdq -> Wqkv_bf[0:704,2048]
    cvt_region(Wdq_w, Wqkv_bf, 682, 2048, 2048, bx * 256 + threadIdx.x);
  } else if (bx < 14336) {              // Wdkv -> Wqkv_bf[704:1792]
    cvt_region(Wdkv_w, Wqkv_bf + 704L * 2048, 1088, 2048, 2048,
               (bx - 5632) * 256 + threadIdx.x);
  } else if (bx < 19968) {              // Wuq [2048 x 704 pad]
    cvt_region(Wuq_w, Wuq_bf, 2048, 682, 704, (bx - 14336) * 256 + threadIdx.x);
  } else if (bx < 32256) {              // Wukv [3072 x 1024]
    cvt_region(Wukv_w, Wukv_bf, 3072, 1024, 1024, (bx - 19968) * 256 + threadIdx.x);
  } else if (bx < 48640) {              // Wo [2048 x 2048]
    cvt_region(Wo_w, Wo_bf, 2048, 2048, 2048, (bx - 32256) * 256 + threadIdx.x);
  } else {                              // bias_qkv[1792]
    int i = (int)(bx - 48640) * 256 + threadIdx.x;
    if (i < NQKV)
      bias_qkv[i] = (i < DQ) ? Wdq_b[i] : ((i < DQP) ? 0.f : Wdkv_b[i - DQP]);
  }
}

// ---------------------------------------------------------------------------
__device__ __forceinline__ float block_sum(float v, float* sbuf) {
#pragma unroll
  for (int off = 32; off > 0; off >>= 1) v += __shfl_down(v, off, 64);
  int wid = threadIdx.x >> 6;
  __syncthreads();
  if ((threadIdx.x & 63) == 0) sbuf[wid] = v;
  __syncthreads();
  return sbuf[0] + sbuf[1] + sbuf[2] + sbuf[3];
}

__global__ __launch_bounds__(256) void ln_bf16_kernel(
    const float* __restrict__ in, int istride,
    unsigned short* __restrict__ out, int ocols,
    const float* __restrict__ g, const float* __restrict__ bta, int D)
{
  __shared__ float sbuf[4];
  size_t row = blockIdx.x;
  const float* xr = in + row * istride;
  float s = 0.f;
  for (int i = threadIdx.x; i < D; i += 256) s += xr[i];
  float mu = block_sum(s, sbuf) / (float)D;
  float v = 0.f;
  for (int i = threadIdx.x; i < D; i += 256) { float d = xr[i] - mu; v += d * d; }
  float var = block_sum(v, sbuf) / (float)D;
  float rstd = rsqrtf(var + 1e-5f);
  unsigned short* orow = out + row * ocols;
  for (int i = threadIdx.x; i < ocols; i += 256)
    orow[i] = (i < D) ? f2bf((xr[i] - mu) * rstd * g[i] + bta[i]) : 0;
}

// ---------------------------------------------------------------------------
// K_blk: per (bh, kt) contiguous 8192-elem tile [c=4][row64][32] (attention
// LDS image). d<64 from kv_bf; d>=64 from c_qkv cols 1728.. (k rotary
// identity per reference quirk). c_qkv stride NQKV.
// ---------------------------------------------------------------------------
__global__ __launch_bounds__(256) void repack_k_blk(
    const unsigned short* __restrict__ kv_bf, const float* __restrict__ cqkv,
    unsigned short* __restrict__ K)
{
  int idx = blockIdx.x * 256 + threadIdx.x;
  int dlow = idx & 31;
  int tt   = (idx >> 5) & 63;
  int dhi  = (idx >> 11) & 3;
  int kt   = (idx >> 13) & 31;
  int bh   = idx >> 18;
  int d = dhi * 32 + dlow;
  int t = kt * 64 + tt;
  int b = bh >> 4, h = bh & 15;
  unsigned short val;
  if (d < 64)
    val = kv_bf[((size_t)(b * T_SEQ + t)) * DUKV + h * 192 + d];
  else
    val = f2bf(cqkv[((size_t)(b * T_SEQ + t)) * NQKV + 1728 + (d - 64)]);
  K[idx] = val;
}

// ---------------------------------------------------------------------------
// V_blk: per (bh, kt) contiguous 8192-elem tile [c2=2][d128][32] = V^T image.
// ---------------------------------------------------------------------------
__global__ __launch_bounds__(256) void repack_v_blk(
    const unsigned short* __restrict__ kv_bf, unsigned short* __restrict__ V)
{
  __shared__ unsigned short T[64 * 132];
  int kt = blockIdx.x, bh = blockIdx.y;
  int b = bh >> 4, h = bh & 15;
  int tid = threadIdx.x;
#pragma unroll
  for (int p = 0; p < 8; p++) {
    int t = p * 8 + (tid >> 5);
    int dbase = (tid & 31) * 4;
    const unsigned short* src =
        kv_bf + ((size_t)(b * T_SEQ + kt * 64 + t)) * DUKV + h * 192 + 64 + dbase;
    unsigned short v0 = src[0], v1 = src[1], v2 = src[2], v3 = src[3];
    unsigned short* dst = &T[t * 132 + dbase];
    dst[0] = v0; dst[1] = v1; dst[2] = v2; dst[3] = v3;
  }
  __syncthreads();
  unsigned short* out = V + ((size_t)(bh * 32 + kt)) * 8192;
#pragma unroll
  for (int p = 0; p < 4; p++) {
    int o = p * 2048 + tid * 8;
    int c2 = o >> 12;
    int dd = (o >> 5) & 127;
    int tl = o & 31;
    short8 pack;
#pragma unroll
    for (int i = 0; i < 8; i++)
      pack[i] = (short)T[(c2 * 32 + tl + i) * 132 + dd];
    *(short8*)&out[o] = pack;
  }
}

// ---------------------------------------------------------------------------
// attn v3b: S^T-form MFMA flash attention (R8-verified). qt = z ? 15-x : x so
// each CU's block pair has complementary (constant) work.
// ---------------------------------------------------------------------------
__global__ __launch_bounds__(256, 2) void attn_mfma3(
    const unsigned short* __restrict__ Qall,
    const unsigned short* __restrict__ Kblk,
    const unsigned short* __restrict__ Vblk,
    unsigned short* __restrict__ y)
{
  __shared__ __align__(16) unsigned short sm[37376];
  const int x = (int)blockIdx.x;
  const int b = (int)blockIdx.z;
  const int qt = b ? (15 - x) : x;
  const int h = blockIdx.y;
  const int tid = threadIdx.x;
  const int w = tid >> 6, lane = tid & 63, q = lane >> 4, r = lane & 15;
  const int bh = b * NH + h;

  short8 qb[2][4];
#pragma unroll
  for (int g = 0; g < 2; g++) {
    const unsigned short* Qrow =
        Qall + ((size_t)bh * T_SEQ + (size_t)qt * 128 + w * 32 + g * 16 + r) * 128 + q * 8;
#pragma unroll
    for (int c = 0; c < 4; c++) qb[g][c] = *(const short8*)(Qrow + c * 32);
  }

  floatx4 oacc[2][8];
#pragma unroll
  for (int g = 0; g < 2; g++)
#pragma unroll
    for (int jd = 0; jd < 8; jd++) oacc[g][jd] = (floatx4){0.f, 0.f, 0.f, 0.f};
  float m_i[2] = {-3.0e38f, -3.0e38f}, l_i[2] = {0.f, 0.f};

  const char* Kg0 = (const char*)(Kblk + ((size_t)(bh * 32)) * 8192);
  const char* Vg0 = (const char*)(Vblk + ((size_t)(bh * 32)) * 8192);
  char* smB = (char*)sm;
  unsigned short* Psw = sm + 32768 + w * 1152;
  const int ktmax = 2 * qt + 1;

#pragma unroll
  for (int i = 0; i < 4; i++) {
    async16(Kg0 + i * 4096 + w * 1024 + lane * 16, smB + i * 4096 + w * 1024);
    async16(Vg0 + i * 4096 + w * 1024 + lane * 16, smB + 32768 + i * 4096 + w * 1024);
  }

  for (int kt = 0; kt <= ktmax; kt++) {
    const int cur = kt & 1;
    __syncthreads();
    if (kt < ktmax) {
      const int nxt = cur ^ 1;
      const char* Kg = Kg0 + (size_t)(kt + 1) * 16384;
      const char* Vg = Vg0 + (size_t)(kt + 1) * 16384;
#pragma unroll
      for (int i = 0; i < 4; i++) {
        async16(Kg + i * 4096 + w * 1024 + lane * 16,
                smB + nxt * 16384 + i * 4096 + w * 1024);
        async16(Vg + i * 4096 + w * 1024 + lane * 16,
                smB + 32768 + nxt * 16384 + i * 4096 + w * 1024);
      }
    }

    const bool activeW = (kt * 64 <= qt * 128 + w * 32 + 31);
    if (activeW) {
      const unsigned short* KsC = sm + cur * 8192;
      const unsigned short* VsC = sm + 16384 + cur * 8192;

      floatx4 sacc[2][4];
#pragma unroll
      for (int g = 0; g < 2; g++)
#pragma unroll
        for (int j = 0; j < 4; j++) sacc[g][j] = (floatx4){0.f, 0.f, 0.f, 0.f};
#pragma unroll
      for (int c = 0; c < 4; c++) {
        short8 ak[4];
#pragma unroll
        for (int j = 0; j < 4; j++)
          ak[j] = *(const short8*)&KsC[c * 2048 + (j * 16 + r) * 32 + q * 8];
#pragma unroll
        for (int g = 0; g < 2; g++)
#pragma unroll
          for (int j = 0; j < 4; j++)
            sacc[g][j] = __builtin_amdgcn_mfma_f32_16x16x32_bf16(ak[j], qb[g][c], sacc[g][j], 0, 0, 0);
      }

#pragma unroll
      for (int g = 0; g < 2; g++) {
        float sv[16];
#pragma unroll
        for (int j = 0; j < 4; j++)
#pragma unroll
          for (int v = 0; v < 4; v++) sv[j * 4 + v] = sacc[g][j][v];
        const int rel = qt * 128 + w * 32 + g * 16 + r - kt * 64;
        if (rel < 63) {
#pragma unroll
          for (int j = 0; j < 4; j++)
#pragma unroll
            for (int v = 0; v < 4; v++)
              if (j * 16 + q * 4 + v > rel) sv[j * 4 + v] = -3.0e38f;
        }
        float rm = sv[0];
#pragma unroll
        for (int t16 = 1; t16 < 16; t16++) rm = fmaxf(rm, sv[t16]);
        rm = fmaxf(rm, __shfl_xor(rm, 16, 64));
        rm = fmaxf(rm, __shfl_xor(rm, 32, 64));
        float mnew = fmaxf(m_i[g], rm);
        float alpha = exp2f(m_i[g] - mnew);
        m_i[g] = mnew;
        float p[16], rsum = 0.f;
#pragma unroll
        for (int t16 = 0; t16 < 16; t16++) { p[t16] = exp2f(sv[t16] - mnew); rsum += p[t16]; }
        rsum += __shfl_xor(rsum, 16, 64);
        rsum += __shfl_xor(rsum, 32, 64);
        l_i[g] = l_i[g] * alpha + rsum;
#pragma unroll
        for (int jd = 0; jd < 8; jd++) {
          oacc[g][jd][0] *= alpha; oacc[g][jd][1] *= alpha;
          oacc[g][jd][2] *= alpha; oacc[g][jd][3] *= alpha;
        }
#pragma unroll
        for (int j = 0; j < 4; j++) {
          unsigned int lo = (unsigned int)f2bf_fast(p[j * 4 + 0]) |
                            ((unsigned int)f2bf_fast(p[j * 4 + 1]) << 16);
          unsigned int hi = (unsigned int)f2bf_fast(p[j * 4 + 2]) |
                            ((unsigned int)f2bf_fast(p[j * 4 + 3]) << 16);
          uint2v pk; pk[0] = lo; pk[1] = hi;
          *(uint2v*)&Psw[r * 72 + j * 16 + q * 4] = pk;
        }
#pragma unroll
        for (int c2 = 0; c2 < 2; c2++) {
          short8 pb = *(const short8*)&Psw[r * 72 + c2 * 32 + q * 8];
#pragma unroll
          for (int jd = 0; jd < 8; jd++) {
            short8 bv = *(const short8*)&VsC[c2 * 4096 + (jd * 16 + r) * 32 + q * 8];
            oacc[g][jd] = __builtin_amdgcn_mfma_f32_16x16x32_bf16(bv, pb, oacc[g][jd], 0, 0, 0);
          }
        }
      }
    }
  }

#pragma unroll
  for (int g = 0; g < 2; g++) {
    float inv = 1.0f / l_i[g];
    unsigned short* yr =
        y + ((size_t)(b * T_SEQ) + (size_t)qt * 128 + w * 32 + g * 16 + r) * DM + h * 128;
#pragma unroll
    for (int jd = 0; jd < 8; jd++) {
      unsigned short o0 = f2bf(oacc[g][jd][0] * inv);
      unsigned short o1 = f2bf(oacc[g][jd][1] * inv);
      unsigned short o2 = f2bf(oacc[g][jd][2] * inv);
      unsigned short o3 = f2bf(oacc[g][jd][3] * inv);
      unsigned int lo = (unsigned int)o0 | ((unsigned int)o1 << 16);
      unsigned int hi = (unsigned int)o2 | ((unsigned int)o3 << 16);
      unsigned int* dst = (unsigned int*)(yr + jd * 16 + q * 4);
      dst[0] = lo; dst[1] = hi;
    }
  }
}

// ---------------------------------------------------------------------------
extern "C" void kernel_launch(void* const* d_in, const int* in_sizes, int n_in,
                              void* d_out, int out_size, void* d_ws, size_t ws_size,
                              hipStream_t stream) {
  const float* x      = (const float*)d_in[0];
  const float* Wdq_w  = (const float*)d_in[1];
  const float* Wdq_b  = (const float*)d_in[2];
  const float* qn_g   = (const float*)d_in[3];
  const float* qn_b   = (const float*)d_in[4];
  const float* Wuq_w  = (const float*)d_in[5];
  const float* Wuq_b  = (const float*)d_in[6];
  const float* Wdkv_w = (const float*)d_in[7];
  const float* Wdkv_b = (const float*)d_in[8];
  const float* kvn_g  = (const float*)d_in[9];
  const float* kvn_b  = (const float*)d_in[10];
  const float* Wukv_w = (const float*)d_in[11];
  const float* Wukv_b = (const float*)d_in[12];
  const float* Wo_w   = (const float*)d_in[13];
  const float* Wo_b   = (const float*)d_in[14];
  float* out = (float*)d_out;

  float* ws = (float*)d_ws;
  unsigned short* x_bf    = (unsigned short*)(ws);              // dies after c_qkv gemm
  unsigned short* y_bf    = (unsigned short*)(ws);              // alias: attn output
  unsigned short* Wqkv_bf = (unsigned short*)(ws + 4194304);    // 1792x2048
  unsigned short* Wuq_bf  = (unsigned short*)(ws + 6029312);    // 2048x704
  unsigned short* Wukv_bf = (unsigned short*)(ws + 6750208);    // 3072x1024
  float* bias_qkv = ws + 8323072;                               // 1792
  float* c_qkv    = ws + 8324864;                               // 4096x1792 fp32
  unsigned short* c_q_bf = (unsigned short*)(ws + 15664896);    // 4096x704
  unsigned short* kvn_bf = (unsigned short*)(ws + 17106688);    // 4096x1024
  unsigned short* kv_bf  = (unsigned short*)(ws + 19203840);    // 4096x3072
  unsigned short* Q_all  = (unsigned short*)(ws + 25495296);    // 2x16x2048x128
  unsigned short* K_blk  = (unsigned short*)(ws + 29689600);
  unsigned short* V_blk  = (unsigned short*)(ws + 33883904);
  unsigned short* Wo_bf  = (unsigned short*)(ws + 38078208);    // 2048x2048

  dim3 blk(256);

  // input + weight prep (2 launches)
  cvt_bf16_pad<<<(4096L*2048 + 255) / 256, blk, 0, stream>>>(x, x_bf, 4096, 2048, 2048, 4096L*2048);
  prep_weights<<<48647, blk, 0, stream>>>(Wdq_w, Wdkv_w, Wuq_w, Wukv_w, Wo_w,
                                          Wdq_b, Wdkv_b,
                                          Wqkv_bf, Wuq_bf, Wukv_bf, Wo_bf, bias_qkv);

  // merged c_qkv = x @ [Wdq; Wdkv]^T + bias   (N=1792, 448 blocks, dbuf)
  gemm_bf16_db<<<dim3(14, 32), blk, 0, stream>>>(x_bf, 2048, Wqkv_bf, 2048, bias_qkv, c_qkv, NQKV, NQKV, 2048);
  // LN q: cols [0,682) ; LN kv: cols [704, 1728)
  ln_bf16_kernel<<<TOK, blk, 0, stream>>>(c_qkv, NQKV, c_q_bf, DQP, qn_g, qn_b, DQ);
  ln_bf16_kernel<<<TOK, blk, 0, stream>>>(c_qkv + DQP, NQKV, kvn_bf, DKV, kvn_g, kvn_b, DKV);
  // fused up-projections: qrope (bx<16) + kv-up (bx>=16), 1280 blocks, dbuf
  gemm_up_fused<<<dim3(40, 32), blk, 0, stream>>>(c_q_bf, Wuq_bf, Wuq_b, Q_all,
                                                  kvn_bf, Wukv_bf, Wukv_b, kv_bf);
  // K/V tile caches
  repack_k_blk<<<(2 * NH * T_SEQ * 128) / 256, blk, 0, stream>>>(kv_bf, c_qkv, K_blk);
  repack_v_blk<<<dim3(32, 32), blk, 0, stream>>>(kv_bf, V_blk);
  // attention
  attn_mfma3<<<dim3(16, 16, 2), blk, 0, stream>>>(Q_all, K_blk, V_blk, y_bf);
  // out = y @ Wo^T + b  (dbuf)
  gemm_bf16_db<<<dim3(16, 32), blk, 0, stream>>>(y_bf, 2048, Wo_bf, 2048, Wo_b, out, DM, DM, 2048);
}